// Round 4
// baseline (10241.454 us; speedup 1.0000x reference)
//
#include <hip/hip_runtime.h>

constexpr int N_ = 20000;
constexpr int E_ = 400000;

#define DEV __device__ __forceinline__

// order-preserving float<->uint for atomicMax (unsigned)
DEV unsigned int fenc(float f) {
    unsigned int i = __float_as_uint(f);
    return (i & 0x80000000u) ? ~i : (i | 0x80000000u);
}
DEV float fdec(unsigned int u) {
    return (u & 0x80000000u) ? __uint_as_float(u ^ 0x80000000u) : __uint_as_float(~u);
}

// ---------------------------------------------------------------- ws-too-small marker
__global__ void k_marker(float* h_out, float v) {
    if (threadIdx.x == 0) h_out[0] = v;
}

// ---------------------------------------------------------------- zero a uint span (s, m, agg, cagg)
__global__ __launch_bounds__(256) void k_zero(unsigned int* p, int n) {
    int i = blockIdx.x * 256 + threadIdx.x;
    if (i < n) p[i] = 0u;
}

// ---------------------------------------------------------------- hq[n][d] = sum_k h[n][k] Wq[k][d] + bq[d]
__global__ __launch_bounds__(256) void k_hq(
    const float* __restrict__ h, const float* __restrict__ Wq, const float* __restrict__ bq,
    float* __restrict__ hq) {
    int idx = blockIdx.x * 256 + threadIdx.x;      // N*128 exact
    int n = idx >> 7, d = idx & 127;
    float acc = 0.f;
    for (int k = 0; k < 128; ++k)
        acc += h[(size_t)n * 128 + k] * Wq[k * 128 + d];
    hq[idx] = acc + bq[d];
}

// ---------------------------------------------------------------- per edge: alpha + segment max (direct k)
// one wave per edge, 4 waves/block
__global__ __launch_bounds__(256) void k_alpha(
    const int* __restrict__ edge_index, const float* __restrict__ coord,
    const float* __restrict__ edge_attr, const float* __restrict__ h,
    const float* __restrict__ Wkv, const float* __restrict__ bkv,
    const float* __restrict__ hq, float* __restrict__ alpha, unsigned int* __restrict__ m) {
    __shared__ float tf[4][160];
    int wv = threadIdx.x >> 6, lane = threadIdx.x & 63;
    int e = blockIdx.x * 4 + wv;
    int row = edge_index[e], col = edge_index[E_ + e];
    // build target_feat = [radial(16), h[col](128), edge_attr(16)]
    if (lane < 16) {
        int c = lane >> 2, f = lane & 3;
        float rj = 0.f;
#pragma unroll
        for (int x = 0; x < 3; ++x) {
            float a = coord[(size_t)row * 12 + c * 3 + x] - coord[(size_t)col * 12 + c * 3 + x];
            float b = coord[(size_t)row * 12 + f * 3 + x] - coord[(size_t)col * 12 + f * 3 + x];
            rj += a * b;
        }
        tf[wv][lane] = rj;
    }
    for (int f = lane; f < 128; f += 64) tf[wv][16 + f] = h[(size_t)col * 128 + f];
    if (lane >= 48) tf[wv][144 + lane - 48] = edge_attr[(size_t)e * 16 + lane - 48];
    __syncthreads();
    // k[d] for d = lane and d = 64+lane (even columns of Wkv), then p = q.k
    float k0 = bkv[2 * lane], k1 = bkv[2 * (64 + lane)];
    for (int f = 0; f < 160; ++f) {
        float tfv = tf[wv][f];
        k0 += tfv * Wkv[f * 256 + 2 * lane];
        k1 += tfv * Wkv[f * 256 + 128 + 2 * lane];
    }
    float p = hq[(size_t)row * 128 + lane] * k0 + hq[(size_t)row * 128 + 64 + lane] * k1;
#pragma unroll
    for (int mm = 32; mm; mm >>= 1) p += __shfl_xor(p, mm);
    if (lane == 0) {
        alpha[e] = p;
        atomicMax(&m[row], fenc(p));
    }
}

// ---------------------------------------------------------------- s[row] += exp(alpha - m[row])
__global__ __launch_bounds__(256) void k_expsum(
    const int* __restrict__ edge_index, const float* __restrict__ alpha,
    const unsigned int* __restrict__ m, float* __restrict__ s) {
    int e = blockIdx.x * 256 + threadIdx.x;
    if (e < E_) {
        int row = edge_index[e];
        atomicAdd(&s[row], __expf(alpha[e] - fdec(m[row])));
    }
}

// ---------------------------------------------------------------- per edge: v, agg, coord path (direct)
__global__ __launch_bounds__(256) void k_edge2(
    const int* __restrict__ edge_index, const float* __restrict__ coord,
    const float* __restrict__ edge_attr, const float* __restrict__ h,
    const float* __restrict__ Wkv, const float* __restrict__ bkv,
    const float* __restrict__ Wc1, const float* __restrict__ Wc2,
    const float* __restrict__ alpha, const unsigned int* __restrict__ m, const float* __restrict__ s,
    float* __restrict__ agg, float* __restrict__ cagg, float* __restrict__ att_out) {
    __shared__ float tf[4][160];
    __shared__ float vsh[4][128];
    int wv = threadIdx.x >> 6, lane = threadIdx.x & 63;
    int e = blockIdx.x * 4 + wv;
    int row = edge_index[e], col = edge_index[E_ + e];
    if (lane < 16) {
        int c = lane >> 2, f = lane & 3;
        float rj = 0.f;
#pragma unroll
        for (int x = 0; x < 3; ++x) {
            float a = coord[(size_t)row * 12 + c * 3 + x] - coord[(size_t)col * 12 + c * 3 + x];
            float b = coord[(size_t)row * 12 + f * 3 + x] - coord[(size_t)col * 12 + f * 3 + x];
            rj += a * b;
        }
        tf[wv][lane] = rj;
    }
    for (int f = lane; f < 128; f += 64) tf[wv][16 + f] = h[(size_t)col * 128 + f];
    if (lane >= 48) tf[wv][144 + lane - 48] = edge_attr[(size_t)e * 16 + lane - 48];
    __syncthreads();
    // v[d] for d = lane, 64+lane (odd columns of Wkv)
    float v0 = bkv[2 * lane + 1], v1 = bkv[2 * (64 + lane) + 1];
    for (int f = 0; f < 160; ++f) {
        float tfv = tf[wv][f];
        v0 += tfv * Wkv[f * 256 + 2 * lane + 1];
        v1 += tfv * Wkv[f * 256 + 129 + 2 * lane];
    }
    float att = __expf(alpha[e] - fdec(m[row])) / s[row];
    atomicAdd(&agg[(size_t)row * 128 + lane], att * v0);
    atomicAdd(&agg[(size_t)row * 128 + 64 + lane], att * v1);
    vsh[wv][lane] = v0;
    vsh[wv][64 + lane] = v1;
    __syncthreads();
    // coord_v = silu(v @ Wc1) @ Wc2   (512 hidden, each lane does 8 hidden units)
    float cv[4] = {0.f, 0.f, 0.f, 0.f};
    for (int g = 0; g < 8; ++g) {
        int jc = g * 64 + lane;
        float u = 0.f;
        for (int dd = 0; dd < 128; ++dd) u += vsh[wv][dd] * Wc1[dd * 512 + jc];
        float su = u / (1.f + __expf(-u));
#pragma unroll
        for (int c = 0; c < 4; ++c) cv[c] += su * Wc2[jc * 4 + c];
    }
#pragma unroll
    for (int mm = 32; mm; mm >>= 1)
#pragma unroll
        for (int c = 0; c < 4; ++c) cv[c] += __shfl_xor(cv[c], mm);
    if (lane < 12) {
        int c = lane / 3;  // i = c*3 + x
        float cd = coord[(size_t)row * 12 + lane] - coord[(size_t)col * 12 + lane];
        atomicAdd(&cagg[(size_t)row * 12 + lane], att * cv[c] * cd);
    }
    if (lane == 0) att_out[e] = att;
}

// ---------------------------------------------------------------- final: h_out, coord_out
__global__ __launch_bounds__(256) void k_final(
    const float* __restrict__ h, const float* __restrict__ coord,
    const float* __restrict__ agg, const float* __restrict__ cagg,
    float* __restrict__ h_out, float* __restrict__ coord_out) {
    int idx = blockIdx.x * 256 + threadIdx.x;  // N*128 exact
    h_out[idx] = h[idx] + agg[idx];
    if (idx < N_ * 12) {
        float v = fminf(fmaxf(cagg[idx], -10.f), 10.f);
        coord_out[idx] = coord[idx] + v;
    }
}

// ---------------------------------------------------------------- launch
extern "C" void kernel_launch(void* const* d_in, const int* in_sizes, int n_in,
                              void* d_out, int out_size, void* d_ws, size_t ws_size,
                              hipStream_t stream) {
    (void)in_sizes; (void)n_in; (void)out_size;
    const float* h          = (const float*)d_in[0];
    const float* coord      = (const float*)d_in[1];
    const int*   edge_index = (const int*)d_in[2];
    const float* edge_attr  = (const float*)d_in[3];
    const float* Wq         = (const float*)d_in[4];
    const float* bq         = (const float*)d_in[5];
    const float* Wkv        = (const float*)d_in[6];
    const float* bkv        = (const float*)d_in[7];
    const float* Wc1        = (const float*)d_in[8];
    const float* Wc2        = (const float*)d_in[9];

    float* out = (float*)d_out;
    float* h_out = out;
    float* coord_out = out + (size_t)N_ * 128;
    float* att_out = coord_out + (size_t)N_ * 12;

    char* w = (char*)d_ws;
    size_t off = 0;
    auto alloc = [&](size_t bytes) -> void* {
        void* p = w + off;
        off += (bytes + 255) & ~(size_t)255;
        return p;
    };
    // zero-span first: s, m, agg, cagg contiguous
    float* s          = (float*)alloc((size_t)N_ * 4);
    unsigned int* m   = (unsigned int*)alloc((size_t)N_ * 4);
    float* agg        = (float*)alloc((size_t)N_ * 128 * 4);
    float* cagg       = (float*)alloc((size_t)N_ * 12 * 4);
    size_t zero_bytes = off;
    float* hq         = (float*)alloc((size_t)N_ * 128 * 4);
    float* alpha      = (float*)alloc((size_t)E_ * 4);

    if (ws_size < off) {
        float marker = 50000.f + 1000.f * (float)(ws_size >> 20);
        hipLaunchKernelGGL(k_marker, dim3(1), dim3(64), 0, stream, h_out, marker);
        return;
    }

    int zero_n = (int)(zero_bytes / 4);
    hipLaunchKernelGGL(k_zero, dim3((zero_n + 255) / 256), dim3(256), 0, stream,
                       (unsigned int*)s, zero_n);
    hipLaunchKernelGGL(k_hq, dim3(N_ * 128 / 256), dim3(256), 0, stream, h, Wq, bq, hq);
    hipLaunchKernelGGL(k_alpha, dim3(E_ / 4), dim3(256), 0, stream,
                       edge_index, coord, edge_attr, h, Wkv, bkv, hq, alpha, m);
    hipLaunchKernelGGL(k_expsum, dim3((E_ + 255) / 256), dim3(256), 0, stream,
                       edge_index, alpha, m, s);
    hipLaunchKernelGGL(k_edge2, dim3(E_ / 4), dim3(256), 0, stream,
                       edge_index, coord, edge_attr, h, Wkv, bkv, Wc1, Wc2,
                       alpha, m, s, agg, cagg, att_out);
    hipLaunchKernelGGL(k_final, dim3(N_ * 128 / 256), dim3(256), 0, stream,
                       h, coord, agg, cagg, h_out, coord_out);
}

// Round 5
// 6012.211 us; speedup vs baseline: 1.7034x; 1.7034x over previous
//
#include <hip/hip_runtime.h>

typedef unsigned short u16;

constexpr int N_ = 20000;
constexpr int E_ = 400000;

#define DEV __device__ __forceinline__

DEV float bf2f(u16 u) { union { unsigned int i; float f; } x; x.i = ((unsigned int)u) << 16; return x.f; }
DEV u16 f2bf(float f) {
    union { unsigned int i; float f; } x; x.f = f;
    unsigned int i = x.i;
    unsigned int r = i + 0x7FFFu + ((i >> 16) & 1u);
    return (u16)(r >> 16);
}
// order-preserving float<->uint for atomicMax (unsigned)
DEV unsigned int fenc(float f) {
    unsigned int i = __float_as_uint(f);
    return (i & 0x80000000u) ? ~i : (i | 0x80000000u);
}
DEV float fdec(unsigned int u) {
    return (u & 0x80000000u) ? __uint_as_float(u ^ 0x80000000u) : __uint_as_float(~u);
}

// ---------------------------------------------------------------- zero a uint span
__global__ __launch_bounds__(256) void k_zero(unsigned int* p, int n) {
    int i = blockIdx.x * 256 + threadIdx.x;
    if (i < n) p[i] = 0u;
}

// ================================================================ FAST PATH
// ---------------------------------------------------------------- per-node hq / k_h / v_h (8 nodes per block)
__global__ __launch_bounds__(256) void k_node1(
    const float* __restrict__ h, const float* __restrict__ Wq, const float* __restrict__ bq,
    const float* __restrict__ Wkv, const float* __restrict__ bkv,
    float* __restrict__ hq, float* __restrict__ k_h, float* __restrict__ v_h) {
    __shared__ float hl[8][128];
    int t = threadIdx.x;
    int node0 = blockIdx.x * 8;
    for (int u = t; u < 1024; u += 256) hl[u >> 7][u & 127] = h[(size_t)(node0 + (u >> 7)) * 128 + (u & 127)];
    __syncthreads();
    int d = t & 127, half = t >> 7;
    float aq[4] = {0, 0, 0, 0}, ak[4] = {0, 0, 0, 0}, av[4] = {0, 0, 0, 0};
    for (int k = 0; k < 128; ++k) {
        float wq = Wq[k * 128 + d];
        float2 wkv = *(const float2*)(Wkv + (size_t)(16 + k) * 256 + 2 * d);
#pragma unroll
        for (int i = 0; i < 4; ++i) {
            float hv = hl[half * 4 + i][k];
            aq[i] += hv * wq;
            ak[i] += hv * wkv.x;
            av[i] += hv * wkv.y;
        }
    }
    float bqd = bq[d], bk = bkv[2 * d], bv = bkv[2 * d + 1];
#pragma unroll
    for (int i = 0; i < 4; ++i) {
        size_t o = (size_t)(node0 + half * 4 + i) * 128 + d;
        hq[o] = aq[i] + bqd;
        k_h[o] = ak[i] + bk;
        v_h[o] = av[i] + bv;
    }
}

// ---------------------------------------------------------------- composites Cr/Cea (32 x 512)
__global__ __launch_bounds__(256) void k_composites(
    const float* __restrict__ Wkv, const float* __restrict__ Wc1,
    float* __restrict__ Cr, float* __restrict__ Cea) {
    int o = blockIdx.x * 256 + threadIdx.x;   // 16384 exact
    int half = o >> 13;
    int j = (o >> 9) & 15;
    int jc = o & 511;
    int row = half ? (144 + j) : j;
    float acc = 0.f;
    for (int d = 0; d < 128; ++d)
        acc += Wkv[(size_t)row * 256 + 2 * d + 1] * Wc1[(size_t)d * 512 + jc];
    (half ? Cea : Cr)[j * 512 + jc] = acc;
}

// ---------------------------------------------------------------- hqWkr / hqWkea (N x 16 each)
__global__ __launch_bounds__(256) void k_hqw(
    const float* __restrict__ hq, const float* __restrict__ Wkv,
    float* __restrict__ hqWkr, float* __restrict__ hqWkea) {
    int idx = blockIdx.x * 256 + threadIdx.x;   // N*32 exact
    int n = idx >> 5, j5 = idx & 31;
    int j = j5 & 15;
    int wrow = (j5 < 16) ? j : (144 + j);
    float acc = 0.f;
    for (int d = 0; d < 128; ++d) acc += hq[(size_t)n * 128 + d] * Wkv[(size_t)wrow * 256 + 2 * d];
    ((j5 < 16) ? hqWkr : hqWkea)[(size_t)n * 16 + j] = acc;
}

// ---------------------------------------------------------------- vWc1h[n][jc] = (v_h[n] @ Wc1)[jc], bf16 (8 nodes/block)
__global__ __launch_bounds__(256) void k_vwc1(
    const float* __restrict__ v_h, const float* __restrict__ Wc1, u16* __restrict__ vWc1h) {
    __shared__ float vl[8][128];
    int t = threadIdx.x;
    int node0 = blockIdx.x * 8;
    for (int u = t; u < 1024; u += 256) vl[u >> 7][u & 127] = v_h[(size_t)(node0 + (u >> 7)) * 128 + (u & 127)];
    __syncthreads();
    for (int g = 0; g < 2; ++g) {
        int jc = g * 256 + t;
        float acc[8] = {0, 0, 0, 0, 0, 0, 0, 0};
        for (int dd = 0; dd < 128; ++dd) {
            float w = Wc1[(size_t)dd * 512 + jc];
#pragma unroll
            for (int n = 0; n < 8; ++n) acc[n] += vl[n][dd] * w;
        }
#pragma unroll
        for (int n = 0; n < 8; ++n) vWc1h[(size_t)(node0 + n) * 512 + jc] = f2bf(acc[n]);
    }
}

// ---------------------------------------------------------------- alpha (decomposed) + segment max
__global__ __launch_bounds__(256) void k_alpha_fast(
    const int* __restrict__ edge_index, const float* __restrict__ coord,
    const float* __restrict__ edge_attr,
    const float* __restrict__ hq, const float* __restrict__ k_h,
    const float* __restrict__ hqWkr, const float* __restrict__ hqWkea,
    float* __restrict__ alpha, unsigned int* __restrict__ m) {
    int wv = threadIdx.x >> 6, lane = threadIdx.x & 63;
    int e = blockIdx.x * 4 + wv;
    int row = edge_index[e], col = edge_index[E_ + e];
    float p = hq[(size_t)row * 128 + lane] * k_h[(size_t)col * 128 + lane] +
              hq[(size_t)row * 128 + 64 + lane] * k_h[(size_t)col * 128 + 64 + lane];
    if (lane < 16) {
        int c = lane >> 2, f = lane & 3;
        float rj = 0.f;
#pragma unroll
        for (int x = 0; x < 3; ++x) {
            float a = coord[(size_t)row * 12 + c * 3 + x] - coord[(size_t)col * 12 + c * 3 + x];
            float b = coord[(size_t)row * 12 + f * 3 + x] - coord[(size_t)col * 12 + f * 3 + x];
            rj += a * b;
        }
        p += hqWkr[(size_t)row * 16 + lane] * rj;
    } else if (lane < 32) {
        int j = lane - 16;
        p += hqWkea[(size_t)row * 16 + j] * edge_attr[(size_t)e * 16 + j];
    }
#pragma unroll
    for (int mm = 32; mm; mm >>= 1) p += __shfl_xor(p, mm);
    if (lane == 0) {
        alpha[e] = p;
        atomicMax(&m[row], fenc(p));
    }
}

// ---------------------------------------------------------------- s[row] += exp(alpha - m[row])
__global__ __launch_bounds__(256) void k_expsum(
    const int* __restrict__ edge_index, const float* __restrict__ alpha,
    const unsigned int* __restrict__ m, float* __restrict__ s) {
    int e = blockIdx.x * 256 + threadIdx.x;
    if (e < E_) {
        int row = edge_index[e];
        atomicAdd(&s[row], __expf(alpha[e] - fdec(m[row])));
    }
}

// ---------------------------------------------------------------- big edge kernel: att, u-path, all aggregations
// one wave = 4 edges; Ccomb (32x512) + Wc2^T staged in LDS
__global__ __launch_bounds__(256) void k_edge_big(
    const int* __restrict__ edge_index, const float* __restrict__ coord,
    const float* __restrict__ edge_attr,
    const float* __restrict__ Cr, const float* __restrict__ Cea, const float* __restrict__ Wc2,
    const u16* __restrict__ vWc1h, const float* __restrict__ v_h,
    const float* __restrict__ alpha, const unsigned int* __restrict__ m, const float* __restrict__ s,
    float* __restrict__ agg, float* __restrict__ cagg,
    float* __restrict__ nodeXr, float* __restrict__ nodeXea, float* __restrict__ att_out) {
    __shared__ float Cc[32 * 512];   // 64 KB: rows 0..15 = Cr, 16..31 = Cea
    __shared__ float W2t[4 * 512];   // 8 KB transposed Wc2
    int t = threadIdx.x;
    for (int i = t; i < 8192; i += 256) { Cc[i] = Cr[i]; Cc[8192 + i] = Cea[i]; }
    for (int i = t; i < 2048; i += 256) W2t[(i & 3) * 512 + (i >> 2)] = Wc2[i];
    __syncthreads();
    int wv = t >> 6, lane = t & 63;
    int i_e = lane >> 4;     // which edge of the quad this lane serves for X/att/cagg
    int j16 = lane & 15;
    int gw = blockIdx.x * 4 + wv;
    int wstride = gridDim.x * 4;
    for (int qi = gw; qi < E_ / 4; qi += wstride) {
        int e0 = qi * 4;
        int rows[4], cols[4];
#pragma unroll
        for (int i = 0; i < 4; ++i) {
            rows[i] = edge_index[e0 + i];
            cols[i] = edge_index[E_ + e0 + i];
        }
        int row = rows[i_e], col = cols[i_e];
        int e = e0 + i_e;
        // per-lane X entries (radial j16, edge_attr j16) for edge i_e
        float Xr, Xea;
        {
            int c = j16 >> 2, f = j16 & 3;
            float rj = 0.f;
#pragma unroll
            for (int x = 0; x < 3; ++x) {
                float a = coord[(size_t)row * 12 + c * 3 + x] - coord[(size_t)col * 12 + c * 3 + x];
                float b = coord[(size_t)row * 12 + f * 3 + x] - coord[(size_t)col * 12 + f * 3 + x];
                rj += a * b;
            }
            Xr = rj;
            Xea = edge_attr[(size_t)e * 16 + j16];
        }
        float att = __expf(alpha[e] - fdec(m[row])) / s[row];
        // u[i][g] over jc = g*64 + lane
        float u[4][8];
#pragma unroll
        for (int i = 0; i < 4; ++i)
#pragma unroll
            for (int g = 0; g < 8; ++g)
                u[i][g] = bf2f(vWc1h[(size_t)cols[i] * 512 + g * 64 + lane]);
        for (int j = 0; j < 16; ++j) {
            float xj[4];
#pragma unroll
            for (int i = 0; i < 4; ++i) xj[i] = __shfl(Xr, i * 16 + j);
            float cj[8];
#pragma unroll
            for (int g = 0; g < 8; ++g) cj[g] = Cc[j * 512 + g * 64 + lane];
#pragma unroll
            for (int i = 0; i < 4; ++i)
#pragma unroll
                for (int g = 0; g < 8; ++g) u[i][g] += xj[i] * cj[g];
        }
        for (int j = 0; j < 16; ++j) {
            float xj[4];
#pragma unroll
            for (int i = 0; i < 4; ++i) xj[i] = __shfl(Xea, i * 16 + j);
            float cj[8];
#pragma unroll
            for (int g = 0; g < 8; ++g) cj[g] = Cc[(16 + j) * 512 + g * 64 + lane];
#pragma unroll
            for (int i = 0; i < 4; ++i)
#pragma unroll
                for (int g = 0; g < 8; ++g) u[i][g] += xj[i] * cj[g];
        }
        // silu + @Wc2 (partial per lane), then wave reduce
        float cv[4][4];
#pragma unroll
        for (int i = 0; i < 4; ++i)
#pragma unroll
            for (int c = 0; c < 4; ++c) cv[i][c] = 0.f;
#pragma unroll
        for (int i = 0; i < 4; ++i)
#pragma unroll
            for (int g = 0; g < 8; ++g) {
                float uv = u[i][g];
                float su = uv / (1.f + __expf(-uv));
                int jc = g * 64 + lane;
#pragma unroll
                for (int c = 0; c < 4; ++c) cv[i][c] += su * W2t[c * 512 + jc];
            }
#pragma unroll
        for (int mm = 32; mm; mm >>= 1)
#pragma unroll
            for (int i = 0; i < 4; ++i)
#pragma unroll
                for (int c = 0; c < 4; ++c) cv[i][c] += __shfl_xor(cv[i][c], mm);
        // cagg (12 per edge)
        if (j16 < 12) {
            float cd = coord[(size_t)row * 12 + j16] - coord[(size_t)col * 12 + j16];
            atomicAdd(&cagg[(size_t)row * 12 + j16], att * cv[i_e][j16 / 3] * cd);
        }
        // attX (32 per edge)
        atomicAdd(&nodeXr[(size_t)row * 16 + j16], att * Xr);
        atomicAdd(&nodeXea[(size_t)row * 16 + j16], att * Xea);
        // agg: sum att * v_h[col]
#pragma unroll
        for (int i = 0; i < 4; ++i) {
            float av = __shfl(att, i * 16);
            atomicAdd(&agg[(size_t)rows[i] * 128 + lane], av * v_h[(size_t)cols[i] * 128 + lane]);
            atomicAdd(&agg[(size_t)rows[i] * 128 + 64 + lane], av * v_h[(size_t)cols[i] * 128 + 64 + lane]);
        }
        if (j16 == 0) att_out[e] = att;
    }
}

// ---------------------------------------------------------------- final: h_out (+attX terms), coord_out
__global__ __launch_bounds__(256) void k_final_fast(
    const float* __restrict__ h, const float* __restrict__ coord,
    const float* __restrict__ agg, const float* __restrict__ cagg,
    const float* __restrict__ nodeXr, const float* __restrict__ nodeXea,
    const float* __restrict__ Wkv,
    float* __restrict__ h_out, float* __restrict__ coord_out) {
    int idx = blockIdx.x * 256 + threadIdx.x;  // N*128 exact
    int n = idx >> 7, d = idx & 127;
    float acc = agg[idx];
#pragma unroll
    for (int j = 0; j < 16; ++j) {
        acc += nodeXr[(size_t)n * 16 + j] * Wkv[(size_t)j * 256 + 2 * d + 1];
        acc += nodeXea[(size_t)n * 16 + j] * Wkv[(size_t)(144 + j) * 256 + 2 * d + 1];
    }
    h_out[idx] = h[idx] + acc;
    if (idx < N_ * 12) {
        float v = fminf(fmaxf(cagg[idx], -10.f), 10.f);
        coord_out[idx] = coord[idx] + v;
    }
}

// ================================================================ SLOW (validated) FALLBACK PATH
__global__ __launch_bounds__(256) void k_hq_slow(
    const float* __restrict__ h, const float* __restrict__ Wq, const float* __restrict__ bq,
    float* __restrict__ hq) {
    int idx = blockIdx.x * 256 + threadIdx.x;
    int n = idx >> 7, d = idx & 127;
    float acc = 0.f;
    for (int k = 0; k < 128; ++k) acc += h[(size_t)n * 128 + k] * Wq[k * 128 + d];
    hq[idx] = acc + bq[d];
}

__global__ __launch_bounds__(256) void k_alpha_slow(
    const int* __restrict__ edge_index, const float* __restrict__ coord,
    const float* __restrict__ edge_attr, const float* __restrict__ h,
    const float* __restrict__ Wkv, const float* __restrict__ bkv,
    const float* __restrict__ hq, float* __restrict__ alpha, unsigned int* __restrict__ m) {
    __shared__ float tf[4][160];
    int wv = threadIdx.x >> 6, lane = threadIdx.x & 63;
    int e = blockIdx.x * 4 + wv;
    int row = edge_index[e], col = edge_index[E_ + e];
    if (lane < 16) {
        int c = lane >> 2, f = lane & 3;
        float rj = 0.f;
#pragma unroll
        for (int x = 0; x < 3; ++x) {
            float a = coord[(size_t)row * 12 + c * 3 + x] - coord[(size_t)col * 12 + c * 3 + x];
            float b = coord[(size_t)row * 12 + f * 3 + x] - coord[(size_t)col * 12 + f * 3 + x];
            rj += a * b;
        }
        tf[wv][lane] = rj;
    }
    for (int f = lane; f < 128; f += 64) tf[wv][16 + f] = h[(size_t)col * 128 + f];
    if (lane >= 48) tf[wv][144 + lane - 48] = edge_attr[(size_t)e * 16 + lane - 48];
    __syncthreads();
    float k0 = bkv[2 * lane], k1 = bkv[2 * (64 + lane)];
    for (int f = 0; f < 160; ++f) {
        float tfv = tf[wv][f];
        k0 += tfv * Wkv[f * 256 + 2 * lane];
        k1 += tfv * Wkv[f * 256 + 128 + 2 * lane];
    }
    float p = hq[(size_t)row * 128 + lane] * k0 + hq[(size_t)row * 128 + 64 + lane] * k1;
#pragma unroll
    for (int mm = 32; mm; mm >>= 1) p += __shfl_xor(p, mm);
    if (lane == 0) {
        alpha[e] = p;
        atomicMax(&m[row], fenc(p));
    }
}

__global__ __launch_bounds__(256) void k_edge2_slow(
    const int* __restrict__ edge_index, const float* __restrict__ coord,
    const float* __restrict__ edge_attr, const float* __restrict__ h,
    const float* __restrict__ Wkv, const float* __restrict__ bkv,
    const float* __restrict__ Wc1, const float* __restrict__ Wc2,
    const float* __restrict__ alpha, const unsigned int* __restrict__ m, const float* __restrict__ s,
    float* __restrict__ agg, float* __restrict__ cagg, float* __restrict__ att_out) {
    __shared__ float tf[4][160];
    __shared__ float vsh[4][128];
    int wv = threadIdx.x >> 6, lane = threadIdx.x & 63;
    int e = blockIdx.x * 4 + wv;
    int row = edge_index[e], col = edge_index[E_ + e];
    if (lane < 16) {
        int c = lane >> 2, f = lane & 3;
        float rj = 0.f;
#pragma unroll
        for (int x = 0; x < 3; ++x) {
            float a = coord[(size_t)row * 12 + c * 3 + x] - coord[(size_t)col * 12 + c * 3 + x];
            float b = coord[(size_t)row * 12 + f * 3 + x] - coord[(size_t)col * 12 + f * 3 + x];
            rj += a * b;
        }
        tf[wv][lane] = rj;
    }
    for (int f = lane; f < 128; f += 64) tf[wv][16 + f] = h[(size_t)col * 128 + f];
    if (lane >= 48) tf[wv][144 + lane - 48] = edge_attr[(size_t)e * 16 + lane - 48];
    __syncthreads();
    float v0 = bkv[2 * lane + 1], v1 = bkv[2 * (64 + lane) + 1];
    for (int f = 0; f < 160; ++f) {
        float tfv = tf[wv][f];
        v0 += tfv * Wkv[f * 256 + 2 * lane + 1];
        v1 += tfv * Wkv[f * 256 + 129 + 2 * lane];
    }
    float att = __expf(alpha[e] - fdec(m[row])) / s[row];
    atomicAdd(&agg[(size_t)row * 128 + lane], att * v0);
    atomicAdd(&agg[(size_t)row * 128 + 64 + lane], att * v1);
    vsh[wv][lane] = v0;
    vsh[wv][64 + lane] = v1;
    __syncthreads();
    float cv[4] = {0.f, 0.f, 0.f, 0.f};
    for (int g = 0; g < 8; ++g) {
        int jc = g * 64 + lane;
        float u = 0.f;
        for (int dd = 0; dd < 128; ++dd) u += vsh[wv][dd] * Wc1[dd * 512 + jc];
        float su = u / (1.f + __expf(-u));
#pragma unroll
        for (int c = 0; c < 4; ++c) cv[c] += su * Wc2[jc * 4 + c];
    }
#pragma unroll
    for (int mm = 32; mm; mm >>= 1)
#pragma unroll
        for (int c = 0; c < 4; ++c) cv[c] += __shfl_xor(cv[c], mm);
    if (lane < 12) {
        int c = lane / 3;
        float cd = coord[(size_t)row * 12 + lane] - coord[(size_t)col * 12 + lane];
        atomicAdd(&cagg[(size_t)row * 12 + lane], att * cv[c] * cd);
    }
    if (lane == 0) att_out[e] = att;
}

__global__ __launch_bounds__(256) void k_final_slow(
    const float* __restrict__ h, const float* __restrict__ coord,
    const float* __restrict__ agg, const float* __restrict__ cagg,
    float* __restrict__ h_out, float* __restrict__ coord_out) {
    int idx = blockIdx.x * 256 + threadIdx.x;
    h_out[idx] = h[idx] + agg[idx];
    if (idx < N_ * 12) {
        float v = fminf(fmaxf(cagg[idx], -10.f), 10.f);
        coord_out[idx] = coord[idx] + v;
    }
}

// ---------------------------------------------------------------- launch
extern "C" void kernel_launch(void* const* d_in, const int* in_sizes, int n_in,
                              void* d_out, int out_size, void* d_ws, size_t ws_size,
                              hipStream_t stream) {
    (void)in_sizes; (void)n_in; (void)out_size;
    const float* h          = (const float*)d_in[0];
    const float* coord      = (const float*)d_in[1];
    const int*   edge_index = (const int*)d_in[2];
    const float* edge_attr  = (const float*)d_in[3];
    const float* Wq         = (const float*)d_in[4];
    const float* bq         = (const float*)d_in[5];
    const float* Wkv        = (const float*)d_in[6];
    const float* bkv        = (const float*)d_in[7];
    const float* Wc1        = (const float*)d_in[8];
    const float* Wc2        = (const float*)d_in[9];

    float* out = (float*)d_out;
    float* h_out = out;
    float* coord_out = out + (size_t)N_ * 128;
    float* att_out = coord_out + (size_t)N_ * 12;

    char* w = (char*)d_ws;
    size_t off = 0;
    auto alloc = [&](size_t bytes) -> void* {
        void* p = w + off;
        off += (bytes + 255) & ~(size_t)255;
        return p;
    };
    // zero-span first: s, m, agg, cagg, nodeXr, nodeXea contiguous
    float* s          = (float*)alloc((size_t)N_ * 4);
    unsigned int* m   = (unsigned int*)alloc((size_t)N_ * 4);
    float* agg        = (float*)alloc((size_t)N_ * 128 * 4);
    float* cagg       = (float*)alloc((size_t)N_ * 12 * 4);
    float* nodeXr     = (float*)alloc((size_t)N_ * 16 * 4);
    float* nodeXea    = (float*)alloc((size_t)N_ * 16 * 4);
    size_t zero_bytes = off;
    float* hq         = (float*)alloc((size_t)N_ * 128 * 4);
    float* alpha      = (float*)alloc((size_t)E_ * 4);
    size_t slow_req   = off;                       // slow path needs everything above
    float* k_h        = (float*)alloc((size_t)N_ * 128 * 4);
    float* v_h        = (float*)alloc((size_t)N_ * 128 * 4);
    u16*   vWc1h      = (u16*)alloc((size_t)N_ * 512 * 2);
    float* hqWkr      = (float*)alloc((size_t)N_ * 16 * 4);
    float* hqWkea     = (float*)alloc((size_t)N_ * 16 * 4);
    float* Cr         = (float*)alloc(16 * 512 * 4);
    float* Cea        = (float*)alloc(16 * 512 * 4);
    size_t fast_req   = off;

    int zero_n = (int)(zero_bytes / 4);
    hipLaunchKernelGGL(k_zero, dim3((zero_n + 255) / 256), dim3(256), 0, stream,
                       (unsigned int*)s, zero_n);

    if (ws_size >= fast_req) {
        hipLaunchKernelGGL(k_node1, dim3(N_ / 8), dim3(256), 0, stream,
                           h, Wq, bq, Wkv, bkv, hq, k_h, v_h);
        hipLaunchKernelGGL(k_composites, dim3(64), dim3(256), 0, stream, Wkv, Wc1, Cr, Cea);
        hipLaunchKernelGGL(k_hqw, dim3(N_ * 32 / 256), dim3(256), 0, stream, hq, Wkv, hqWkr, hqWkea);
        hipLaunchKernelGGL(k_vwc1, dim3(N_ / 8), dim3(256), 0, stream, v_h, Wc1, vWc1h);
        hipLaunchKernelGGL(k_alpha_fast, dim3(E_ / 4), dim3(256), 0, stream,
                           edge_index, coord, edge_attr, hq, k_h, hqWkr, hqWkea, alpha, m);
        hipLaunchKernelGGL(k_expsum, dim3((E_ + 255) / 256), dim3(256), 0, stream,
                           edge_index, alpha, m, s);
        hipLaunchKernelGGL(k_edge_big, dim3(1024), dim3(256), 0, stream,
                           edge_index, coord, edge_attr, Cr, Cea, Wc2, vWc1h, v_h,
                           alpha, m, s, agg, cagg, nodeXr, nodeXea, att_out);
        hipLaunchKernelGGL(k_final_fast, dim3(N_ * 128 / 256), dim3(256), 0, stream,
                           h, coord, agg, cagg, nodeXr, nodeXea, Wkv, h_out, coord_out);
    } else if (ws_size >= slow_req) {
        hipLaunchKernelGGL(k_hq_slow, dim3(N_ * 128 / 256), dim3(256), 0, stream, h, Wq, bq, hq);
        hipLaunchKernelGGL(k_alpha_slow, dim3(E_ / 4), dim3(256), 0, stream,
                           edge_index, coord, edge_attr, h, Wkv, bkv, hq, alpha, m);
        hipLaunchKernelGGL(k_expsum, dim3((E_ + 255) / 256), dim3(256), 0, stream,
                           edge_index, alpha, m, s);
        hipLaunchKernelGGL(k_edge2_slow, dim3(E_ / 4), dim3(256), 0, stream,
                           edge_index, coord, edge_attr, h, Wkv, bkv, Wc1, Wc2,
                           alpha, m, s, agg, cagg, att_out);
        hipLaunchKernelGGL(k_final_slow, dim3(N_ * 128 / 256), dim3(256), 0, stream,
                           h, coord, agg, cagg, h_out, coord_out);
    }
}

// Round 6
// 5175.094 us; speedup vs baseline: 1.9790x; 1.1618x over previous
//
#include <hip/hip_runtime.h>

typedef unsigned short u16;

constexpr int N_ = 20000;
constexpr int E_ = 400000;

#define DEV __device__ __forceinline__

DEV float bf2f(u16 u) { union { unsigned int i; float f; } x; x.i = ((unsigned int)u) << 16; return x.f; }
DEV u16 f2bf(float f) {
    union { unsigned int i; float f; } x; x.f = f;
    unsigned int i = x.i;
    unsigned int r = i + 0x7FFFu + ((i >> 16) & 1u);
    return (u16)(r >> 16);
}
// order-preserving float<->uint for atomicMax (unsigned) [slow path only]
DEV unsigned int fenc(float f) {
    unsigned int i = __float_as_uint(f);
    return (i & 0x80000000u) ? ~i : (i | 0x80000000u);
}
DEV float fdec(unsigned int u) {
    return (u & 0x80000000u) ? __uint_as_float(u ^ 0x80000000u) : __uint_as_float(~u);
}

// ---------------------------------------------------------------- zero a uint span
__global__ __launch_bounds__(256) void k_zero(unsigned int* p, int n) {
    int i = blockIdx.x * 256 + threadIdx.x;
    if (i < n) p[i] = 0u;
}

// ================================================================ FAST PATH
// ---------------------------------------------------------------- per-node hq / k_h / v_h (8 nodes per block)
__global__ __launch_bounds__(256) void k_node1(
    const float* __restrict__ h, const float* __restrict__ Wq, const float* __restrict__ bq,
    const float* __restrict__ Wkv, const float* __restrict__ bkv,
    float* __restrict__ hq, float* __restrict__ k_h, float* __restrict__ v_h) {
    __shared__ float hl[8][128];
    int t = threadIdx.x;
    int node0 = blockIdx.x * 8;
    for (int u = t; u < 1024; u += 256) hl[u >> 7][u & 127] = h[(size_t)(node0 + (u >> 7)) * 128 + (u & 127)];
    __syncthreads();
    int d = t & 127, half = t >> 7;
    float aq[4] = {0, 0, 0, 0}, ak[4] = {0, 0, 0, 0}, av[4] = {0, 0, 0, 0};
    for (int k = 0; k < 128; ++k) {
        float wq = Wq[k * 128 + d];
        float2 wkv = *(const float2*)(Wkv + (size_t)(16 + k) * 256 + 2 * d);
#pragma unroll
        for (int i = 0; i < 4; ++i) {
            float hv = hl[half * 4 + i][k];
            aq[i] += hv * wq;
            ak[i] += hv * wkv.x;
            av[i] += hv * wkv.y;
        }
    }
    float bqd = bq[d], bk = bkv[2 * d], bv = bkv[2 * d + 1];
#pragma unroll
    for (int i = 0; i < 4; ++i) {
        size_t o = (size_t)(node0 + half * 4 + i) * 128 + d;
        hq[o] = aq[i] + bqd;
        k_h[o] = ak[i] + bk;
        v_h[o] = av[i] + bv;
    }
}

// ---------------------------------------------------------------- composites Cr/Cea (32 x 512)
__global__ __launch_bounds__(256) void k_composites(
    const float* __restrict__ Wkv, const float* __restrict__ Wc1,
    float* __restrict__ Cr, float* __restrict__ Cea) {
    int o = blockIdx.x * 256 + threadIdx.x;   // 16384 exact
    int half = o >> 13;
    int j = (o >> 9) & 15;
    int jc = o & 511;
    int row = half ? (144 + j) : j;
    float acc = 0.f;
    for (int d = 0; d < 128; ++d)
        acc += Wkv[(size_t)row * 256 + 2 * d + 1] * Wc1[(size_t)d * 512 + jc];
    (half ? Cea : Cr)[j * 512 + jc] = acc;
}

// ---------------------------------------------------------------- hqWkr / hqWkea (N x 16 each)
__global__ __launch_bounds__(256) void k_hqw(
    const float* __restrict__ hq, const float* __restrict__ Wkv,
    float* __restrict__ hqWkr, float* __restrict__ hqWkea) {
    int idx = blockIdx.x * 256 + threadIdx.x;   // N*32 exact
    int n = idx >> 5, j5 = idx & 31;
    int j = j5 & 15;
    int wrow = (j5 < 16) ? j : (144 + j);
    float acc = 0.f;
    for (int d = 0; d < 128; ++d) acc += hq[(size_t)n * 128 + d] * Wkv[(size_t)wrow * 256 + 2 * d];
    ((j5 < 16) ? hqWkr : hqWkea)[(size_t)n * 16 + j] = acc;
}

// ---------------------------------------------------------------- vWc1h[n][jc] = (v_h[n] @ Wc1)[jc], bf16 (8 nodes/block)
__global__ __launch_bounds__(256) void k_vwc1(
    const float* __restrict__ v_h, const float* __restrict__ Wc1, u16* __restrict__ vWc1h) {
    __shared__ float vl[8][128];
    int t = threadIdx.x;
    int node0 = blockIdx.x * 8;
    for (int u = t; u < 1024; u += 256) vl[u >> 7][u & 127] = v_h[(size_t)(node0 + (u >> 7)) * 128 + (u & 127)];
    __syncthreads();
    for (int g = 0; g < 2; ++g) {
        int jc = g * 256 + t;
        float acc[8] = {0, 0, 0, 0, 0, 0, 0, 0};
        for (int dd = 0; dd < 128; ++dd) {
            float w = Wc1[(size_t)dd * 512 + jc];
#pragma unroll
            for (int n = 0; n < 8; ++n) acc[n] += vl[n][dd] * w;
        }
#pragma unroll
        for (int n = 0; n < 8; ++n) vWc1h[(size_t)(node0 + n) * 512 + jc] = f2bf(acc[n]);
    }
}

// ---------------------------------------------------------------- alpha (decomposed) + degree histogram
__global__ __launch_bounds__(256) void k_alpha_fast(
    const int* __restrict__ edge_index, const float* __restrict__ coord,
    const float* __restrict__ edge_attr,
    const float* __restrict__ hq, const float* __restrict__ k_h,
    const float* __restrict__ hqWkr, const float* __restrict__ hqWkea,
    float* __restrict__ alpha, int* __restrict__ counts) {
    int wv = threadIdx.x >> 6, lane = threadIdx.x & 63;
    int e = blockIdx.x * 4 + wv;
    int row = edge_index[e], col = edge_index[E_ + e];
    float p = hq[(size_t)row * 128 + lane] * k_h[(size_t)col * 128 + lane] +
              hq[(size_t)row * 128 + 64 + lane] * k_h[(size_t)col * 128 + 64 + lane];
    if (lane < 16) {
        int c = lane >> 2, f = lane & 3;
        float rj = 0.f;
#pragma unroll
        for (int x = 0; x < 3; ++x) {
            float a = coord[(size_t)row * 12 + c * 3 + x] - coord[(size_t)col * 12 + c * 3 + x];
            float b = coord[(size_t)row * 12 + f * 3 + x] - coord[(size_t)col * 12 + f * 3 + x];
            rj += a * b;
        }
        p += hqWkr[(size_t)row * 16 + lane] * rj;
    } else if (lane < 32) {
        int j = lane - 16;
        p += hqWkea[(size_t)row * 16 + j] * edge_attr[(size_t)e * 16 + j];
    }
#pragma unroll
    for (int mm = 32; mm; mm >>= 1) p += __shfl_xor(p, mm);
    if (lane == 0) {
        alpha[e] = p;
        atomicAdd(&counts[row], 1);
    }
}

// ---------------------------------------------------------------- exclusive scan (single block, wave scans)
__global__ __launch_bounds__(1024) void k_scan(const int* __restrict__ counts,
                                               int* __restrict__ offsets, int* __restrict__ cursor) {
    __shared__ int wtot[16];
    int t = threadIdx.x;
    int lane = t & 63, wv = t >> 6;
    int base = 0;
    for (int start = 0; start < N_; start += 1024) {
        int i = start + t;
        int orig = (i < N_) ? counts[i] : 0;
        int v = orig;
#pragma unroll
        for (int off = 1; off < 64; off <<= 1) {
            int x = __shfl_up(v, off);
            if (lane >= off) v += x;
        }
        if (lane == 63) wtot[wv] = v;
        __syncthreads();
        int wbase = 0, chunktot = 0;
#pragma unroll
        for (int k = 0; k < 16; ++k) {
            int wt = wtot[k];
            if (k < wv) wbase += wt;
            chunktot += wt;
        }
        if (i < N_) {
            int excl = base + wbase + v - orig;
            offsets[i] = excl;
            cursor[i] = excl;
        }
        base += chunktot;
        __syncthreads();
    }
    if (t == 0) offsets[N_] = base;
}

// ---------------------------------------------------------------- CSR fill
__global__ void k_fill(const int* __restrict__ edge_index, int* __restrict__ cursor,
                       int* __restrict__ edge_ids) {
    int i = blockIdx.x * 256 + threadIdx.x;
    if (i < E_) {
        int r = edge_index[i];
        int pos = atomicAdd(&cursor[r], 1);
        edge_ids[pos] = i;
    }
}

// ---------------------------------------------------------------- per-edge Z[e][4] = silu(u) @ Wc2 (no atomics)
// u[e][jc] = vWc1h[col[e]][jc] + Xr@Cr + Xea@Cea; 4 edges per wave, grid-stride
__global__ __launch_bounds__(256) void k_edge_z(
    const int* __restrict__ edge_index, const float* __restrict__ coord,
    const float* __restrict__ edge_attr,
    const float* __restrict__ Cr, const float* __restrict__ Cea, const float* __restrict__ Wc2,
    const u16* __restrict__ vWc1h, float* __restrict__ Z) {
    __shared__ float Cc[32 * 512];   // 64 KB
    __shared__ float W2t[4 * 512];   // 8 KB
    int t = threadIdx.x;
    for (int i = t; i < 8192; i += 256) { Cc[i] = Cr[i]; Cc[8192 + i] = Cea[i]; }
    for (int i = t; i < 2048; i += 256) W2t[(i & 3) * 512 + (i >> 2)] = Wc2[i];
    __syncthreads();
    int wv = t >> 6, lane = t & 63;
    int i_e = lane >> 4;
    int j16 = lane & 15;
    int gw = blockIdx.x * 4 + wv;
    int wstride = gridDim.x * 4;
    for (int qi = gw; qi < E_ / 4; qi += wstride) {
        int e0 = qi * 4;
        int cols[4];
#pragma unroll
        for (int i = 0; i < 4; ++i) cols[i] = edge_index[E_ + e0 + i];
        int e = e0 + i_e;
        int row = edge_index[e], col = cols[i_e];
        // per-lane X entries for edge i_e
        float Xr, Xea;
        {
            int c = j16 >> 2, f = j16 & 3;
            float rj = 0.f;
#pragma unroll
            for (int x = 0; x < 3; ++x) {
                float a = coord[(size_t)row * 12 + c * 3 + x] - coord[(size_t)col * 12 + c * 3 + x];
                float b = coord[(size_t)row * 12 + f * 3 + x] - coord[(size_t)col * 12 + f * 3 + x];
                rj += a * b;
            }
            Xr = rj;
            Xea = edge_attr[(size_t)e * 16 + j16];
        }
        float u[4][8];
#pragma unroll
        for (int i = 0; i < 4; ++i)
#pragma unroll
            for (int g = 0; g < 8; ++g)
                u[i][g] = bf2f(vWc1h[(size_t)cols[i] * 512 + g * 64 + lane]);
        for (int j = 0; j < 16; ++j) {
            float xj[4];
#pragma unroll
            for (int i = 0; i < 4; ++i) xj[i] = __shfl(Xr, i * 16 + j);
#pragma unroll
            for (int g = 0; g < 8; ++g) {
                float cj = Cc[j * 512 + g * 64 + lane];
#pragma unroll
                for (int i = 0; i < 4; ++i) u[i][g] += xj[i] * cj;
            }
        }
        for (int j = 0; j < 16; ++j) {
            float xj[4];
#pragma unroll
            for (int i = 0; i < 4; ++i) xj[i] = __shfl(Xea, i * 16 + j);
#pragma unroll
            for (int g = 0; g < 8; ++g) {
                float cj = Cc[(16 + j) * 512 + g * 64 + lane];
#pragma unroll
                for (int i = 0; i < 4; ++i) u[i][g] += xj[i] * cj;
            }
        }
        float cv[4][4];
#pragma unroll
        for (int i = 0; i < 4; ++i)
#pragma unroll
            for (int c = 0; c < 4; ++c) cv[i][c] = 0.f;
#pragma unroll
        for (int i = 0; i < 4; ++i)
#pragma unroll
            for (int g = 0; g < 8; ++g) {
                float uv = u[i][g];
                float su = uv / (1.f + __expf(-uv));
                int jc = g * 64 + lane;
#pragma unroll
                for (int c = 0; c < 4; ++c) cv[i][c] += su * W2t[c * 512 + jc];
            }
#pragma unroll
        for (int mm = 32; mm; mm >>= 1)
#pragma unroll
            for (int i = 0; i < 4; ++i)
#pragma unroll
                for (int c = 0; c < 4; ++c) cv[i][c] += __shfl_xor(cv[i][c], mm);
        if (j16 < 4) Z[(size_t)e * 4 + j16] = cv[i_e][j16];
    }
}

// ---------------------------------------------------------------- per-node softmax + all aggregations (no atomics)
__global__ __launch_bounds__(256) void k_node_main(
    const int* __restrict__ edge_index, const int* __restrict__ offsets, const int* __restrict__ edge_ids,
    const float* __restrict__ alpha, const float* __restrict__ v_h, const float* __restrict__ Z,
    const float* __restrict__ coord, const float* __restrict__ edge_attr, const float* __restrict__ h,
    const float* __restrict__ Wkv, float* __restrict__ h_out, float* __restrict__ coord_out,
    float* __restrict__ att_out) {
    int wv = threadIdx.x >> 6, lane = threadIdx.x & 63;
    int n = blockIdx.x * 4 + wv;
    int beg = offsets[n], end = offsets[n + 1];
    float cn[12];
#pragma unroll
    for (int i = 0; i < 12; ++i) cn[i] = coord[(size_t)n * 12 + i];
    // softmax max
    float mloc = -3.402823466e38f;
    for (int i = beg + lane; i < end; i += 64) mloc = fmaxf(mloc, alpha[edge_ids[i]]);
#pragma unroll
    for (int mm = 32; mm; mm >>= 1) mloc = fmaxf(mloc, __shfl_xor(mloc, mm));
    // softmax sum
    float sloc = 0.f;
    for (int i = beg + lane; i < end; i += 64) sloc += __expf(alpha[edge_ids[i]] - mloc);
#pragma unroll
    for (int mm = 32; mm; mm >>= 1) sloc += __shfl_xor(sloc, mm);
    float inv_s = (end > beg) ? 1.f / sloc : 0.f;
    // lane-parallel pass
    float raggr[16], eaggr[16], cagg[12];
#pragma unroll
    for (int j = 0; j < 16; ++j) { raggr[j] = 0.f; eaggr[j] = 0.f; }
#pragma unroll
    for (int j = 0; j < 12; ++j) cagg[j] = 0.f;
    for (int i = beg + lane; i < end; i += 64) {
        int e = edge_ids[i];
        int col = edge_index[E_ + e];
        float att = __expf(alpha[e] - mloc) * inv_s;
        att_out[e] = att;
        float cd[12];
#pragma unroll
        for (int x = 0; x < 12; ++x) cd[x] = cn[x] - coord[(size_t)col * 12 + x];
#pragma unroll
        for (int c = 0; c < 4; ++c)
#pragma unroll
            for (int f = 0; f < 4; ++f) {
                float r = cd[c * 3] * cd[f * 3] + cd[c * 3 + 1] * cd[f * 3 + 1] + cd[c * 3 + 2] * cd[f * 3 + 2];
                raggr[c * 4 + f] += att * r;
            }
#pragma unroll
        for (int j = 0; j < 16; ++j) eaggr[j] += att * edge_attr[(size_t)e * 16 + j];
        float cv0 = att * Z[(size_t)e * 4 + 0];
        float cv1 = att * Z[(size_t)e * 4 + 1];
        float cv2 = att * Z[(size_t)e * 4 + 2];
        float cv3 = att * Z[(size_t)e * 4 + 3];
#pragma unroll
        for (int x = 0; x < 3; ++x) {
            cagg[0 + x] += cv0 * cd[0 + x];
            cagg[3 + x] += cv1 * cd[3 + x];
            cagg[6 + x] += cv2 * cd[6 + x];
            cagg[9 + x] += cv3 * cd[9 + x];
        }
    }
#pragma unroll
    for (int mm = 32; mm; mm >>= 1) {
#pragma unroll
        for (int j = 0; j < 16; ++j) {
            raggr[j] += __shfl_xor(raggr[j], mm);
            eaggr[j] += __shfl_xor(eaggr[j], mm);
        }
#pragma unroll
        for (int j = 0; j < 12; ++j) cagg[j] += __shfl_xor(cagg[j], mm);
    }
    // wave-cooperative agg (128-dim)
    float agg0 = 0.f, agg1 = 0.f;
    for (int i = beg; i < end; ++i) {
        int e = edge_ids[i];
        int col = edge_index[E_ + e];
        float att = __expf(alpha[e] - mloc) * inv_s;
        agg0 += att * v_h[(size_t)col * 128 + lane];
        agg1 += att * v_h[(size_t)col * 128 + 64 + lane];
    }
#pragma unroll
    for (int g = 0; g < 2; ++g) {
        int dd = g * 64 + lane;
        float acc = g ? agg1 : agg0;
#pragma unroll
        for (int j = 0; j < 16; ++j) {
            acc += raggr[j] * Wkv[(size_t)j * 256 + 2 * dd + 1];
            acc += eaggr[j] * Wkv[(size_t)(144 + j) * 256 + 2 * dd + 1];
        }
        h_out[(size_t)n * 128 + dd] = h[(size_t)n * 128 + dd] + acc;
    }
    if (lane == 0) {
#pragma unroll
        for (int i = 0; i < 12; ++i) {
            float v = fminf(fmaxf(cagg[i], -10.f), 10.f);
            coord_out[(size_t)n * 12 + i] = cn[i] + v;
        }
    }
}

// ================================================================ SLOW (validated) FALLBACK PATH
__global__ __launch_bounds__(256) void k_hq_slow(
    const float* __restrict__ h, const float* __restrict__ Wq, const float* __restrict__ bq,
    float* __restrict__ hq) {
    int idx = blockIdx.x * 256 + threadIdx.x;
    int n = idx >> 7, d = idx & 127;
    float acc = 0.f;
    for (int k = 0; k < 128; ++k) acc += h[(size_t)n * 128 + k] * Wq[k * 128 + d];
    hq[idx] = acc + bq[d];
}

__global__ __launch_bounds__(256) void k_alpha_slow(
    const int* __restrict__ edge_index, const float* __restrict__ coord,
    const float* __restrict__ edge_attr, const float* __restrict__ h,
    const float* __restrict__ Wkv, const float* __restrict__ bkv,
    const float* __restrict__ hq, float* __restrict__ alpha, unsigned int* __restrict__ m) {
    __shared__ float tf[4][160];
    int wv = threadIdx.x >> 6, lane = threadIdx.x & 63;
    int e = blockIdx.x * 4 + wv;
    int row = edge_index[e], col = edge_index[E_ + e];
    if (lane < 16) {
        int c = lane >> 2, f = lane & 3;
        float rj = 0.f;
#pragma unroll
        for (int x = 0; x < 3; ++x) {
            float a = coord[(size_t)row * 12 + c * 3 + x] - coord[(size_t)col * 12 + c * 3 + x];
            float b = coord[(size_t)row * 12 + f * 3 + x] - coord[(size_t)col * 12 + f * 3 + x];
            rj += a * b;
        }
        tf[wv][lane] = rj;
    }
    for (int f = lane; f < 128; f += 64) tf[wv][16 + f] = h[(size_t)col * 128 + f];
    if (lane >= 48) tf[wv][144 + lane - 48] = edge_attr[(size_t)e * 16 + lane - 48];
    __syncthreads();
    float k0 = bkv[2 * lane], k1 = bkv[2 * (64 + lane)];
    for (int f = 0; f < 160; ++f) {
        float tfv = tf[wv][f];
        k0 += tfv * Wkv[f * 256 + 2 * lane];
        k1 += tfv * Wkv[f * 256 + 128 + 2 * lane];
    }
    float p = hq[(size_t)row * 128 + lane] * k0 + hq[(size_t)row * 128 + 64 + lane] * k1;
#pragma unroll
    for (int mm = 32; mm; mm >>= 1) p += __shfl_xor(p, mm);
    if (lane == 0) {
        alpha[e] = p;
        atomicMax(&m[row], fenc(p));
    }
}

__global__ __launch_bounds__(256) void k_expsum_slow(
    const int* __restrict__ edge_index, const float* __restrict__ alpha,
    const unsigned int* __restrict__ m, float* __restrict__ s) {
    int e = blockIdx.x * 256 + threadIdx.x;
    if (e < E_) {
        int row = edge_index[e];
        atomicAdd(&s[row], __expf(alpha[e] - fdec(m[row])));
    }
}

__global__ __launch_bounds__(256) void k_edge2_slow(
    const int* __restrict__ edge_index, const float* __restrict__ coord,
    const float* __restrict__ edge_attr, const float* __restrict__ h,
    const float* __restrict__ Wkv, const float* __restrict__ bkv,
    const float* __restrict__ Wc1, const float* __restrict__ Wc2,
    const float* __restrict__ alpha, const unsigned int* __restrict__ m, const float* __restrict__ s,
    float* __restrict__ agg, float* __restrict__ cagg, float* __restrict__ att_out) {
    __shared__ float tf[4][160];
    __shared__ float vsh[4][128];
    int wv = threadIdx.x >> 6, lane = threadIdx.x & 63;
    int e = blockIdx.x * 4 + wv;
    int row = edge_index[e], col = edge_index[E_ + e];
    if (lane < 16) {
        int c = lane >> 2, f = lane & 3;
        float rj = 0.f;
#pragma unroll
        for (int x = 0; x < 3; ++x) {
            float a = coord[(size_t)row * 12 + c * 3 + x] - coord[(size_t)col * 12 + c * 3 + x];
            float b = coord[(size_t)row * 12 + f * 3 + x] - coord[(size_t)col * 12 + f * 3 + x];
            rj += a * b;
        }
        tf[wv][lane] = rj;
    }
    for (int f = lane; f < 128; f += 64) tf[wv][16 + f] = h[(size_t)col * 128 + f];
    if (lane >= 48) tf[wv][144 + lane - 48] = edge_attr[(size_t)e * 16 + lane - 48];
    __syncthreads();
    float v0 = bkv[2 * lane + 1], v1 = bkv[2 * (64 + lane) + 1];
    for (int f = 0; f < 160; ++f) {
        float tfv = tf[wv][f];
        v0 += tfv * Wkv[f * 256 + 2 * lane + 1];
        v1 += tfv * Wkv[f * 256 + 129 + 2 * lane];
    }
    float att = __expf(alpha[e] - fdec(m[row])) / s[row];
    atomicAdd(&agg[(size_t)row * 128 + lane], att * v0);
    atomicAdd(&agg[(size_t)row * 128 + 64 + lane], att * v1);
    vsh[wv][lane] = v0;
    vsh[wv][64 + lane] = v1;
    __syncthreads();
    float cv[4] = {0.f, 0.f, 0.f, 0.f};
    for (int g = 0; g < 8; ++g) {
        int jc = g * 64 + lane;
        float u = 0.f;
        for (int dd = 0; dd < 128; ++dd) u += vsh[wv][dd] * Wc1[dd * 512 + jc];
        float su = u / (1.f + __expf(-u));
#pragma unroll
        for (int c = 0; c < 4; ++c) cv[c] += su * Wc2[jc * 4 + c];
    }
#pragma unroll
    for (int mm = 32; mm; mm >>= 1)
#pragma unroll
        for (int c = 0; c < 4; ++c) cv[c] += __shfl_xor(cv[c], mm);
    if (lane < 12) {
        int c = lane / 3;
        float cd = coord[(size_t)row * 12 + lane] - coord[(size_t)col * 12 + lane];
        atomicAdd(&cagg[(size_t)row * 12 + lane], att * cv[c] * cd);
    }
    if (lane == 0) att_out[e] = att;
}

__global__ __launch_bounds__(256) void k_final_slow(
    const float* __restrict__ h, const float* __restrict__ coord,
    const float* __restrict__ agg, const float* __restrict__ cagg,
    float* __restrict__ h_out, float* __restrict__ coord_out) {
    int idx = blockIdx.x * 256 + threadIdx.x;
    h_out[idx] = h[idx] + agg[idx];
    if (idx < N_ * 12) {
        float v = fminf(fmaxf(cagg[idx], -10.f), 10.f);
        coord_out[idx] = coord[idx] + v;
    }
}

// ---------------------------------------------------------------- launch
extern "C" void kernel_launch(void* const* d_in, const int* in_sizes, int n_in,
                              void* d_out, int out_size, void* d_ws, size_t ws_size,
                              hipStream_t stream) {
    (void)in_sizes; (void)n_in; (void)out_size;
    const float* h          = (const float*)d_in[0];
    const float* coord      = (const float*)d_in[1];
    const int*   edge_index = (const int*)d_in[2];
    const float* edge_attr  = (const float*)d_in[3];
    const float* Wq         = (const float*)d_in[4];
    const float* bq         = (const float*)d_in[5];
    const float* Wkv        = (const float*)d_in[6];
    const float* bkv        = (const float*)d_in[7];
    const float* Wc1        = (const float*)d_in[8];
    const float* Wc2        = (const float*)d_in[9];

    float* out = (float*)d_out;
    float* h_out = out;
    float* coord_out = out + (size_t)N_ * 128;
    float* att_out = coord_out + (size_t)N_ * 12;

    char* w = (char*)d_ws;
    size_t off = 0;
    auto alloc = [&](size_t bytes) -> void* {
        void* p = w + off;
        off += (bytes + 255) & ~(size_t)255;
        return p;
    };
    // ---- fast-path layout
    int* counts   = (int*)alloc((size_t)N_ * 4);          // zeroed
    size_t zero_bytes = off;
    float* hq     = (float*)alloc((size_t)N_ * 128 * 4);
    float* k_h    = (float*)alloc((size_t)N_ * 128 * 4);
    float* v_h    = (float*)alloc((size_t)N_ * 128 * 4);
    u16*   vWc1h  = (u16*)alloc((size_t)N_ * 512 * 2);
    float* hqWkr  = (float*)alloc((size_t)N_ * 16 * 4);
    float* hqWkea = (float*)alloc((size_t)N_ * 16 * 4);
    float* alpha  = (float*)alloc((size_t)E_ * 4);
    float* Z      = (float*)alloc((size_t)E_ * 4 * 4);
    float* Cr     = (float*)alloc(16 * 512 * 4);
    float* Cea    = (float*)alloc(16 * 512 * 4);
    int* offsets  = (int*)alloc((size_t)(N_ + 1) * 4);
    int* cursor   = (int*)alloc((size_t)N_ * 4);
    int* edge_ids = (int*)alloc((size_t)E_ * 4);
    size_t fast_req = off;

    if (ws_size >= fast_req) {
        hipLaunchKernelGGL(k_zero, dim3((N_ + 255) / 256), dim3(256), 0, stream,
                           (unsigned int*)counts, N_);
        hipLaunchKernelGGL(k_node1, dim3(N_ / 8), dim3(256), 0, stream,
                           h, Wq, bq, Wkv, bkv, hq, k_h, v_h);
        hipLaunchKernelGGL(k_composites, dim3(64), dim3(256), 0, stream, Wkv, Wc1, Cr, Cea);
        hipLaunchKernelGGL(k_hqw, dim3(N_ * 32 / 256), dim3(256), 0, stream, hq, Wkv, hqWkr, hqWkea);
        hipLaunchKernelGGL(k_vwc1, dim3(N_ / 8), dim3(256), 0, stream, v_h, Wc1, vWc1h);
        hipLaunchKernelGGL(k_alpha_fast, dim3(E_ / 4), dim3(256), 0, stream,
                           edge_index, coord, edge_attr, hq, k_h, hqWkr, hqWkea, alpha, counts);
        hipLaunchKernelGGL(k_scan, dim3(1), dim3(1024), 0, stream, counts, offsets, cursor);
        hipLaunchKernelGGL(k_fill, dim3((E_ + 255) / 256), dim3(256), 0, stream,
                           edge_index, cursor, edge_ids);
        hipLaunchKernelGGL(k_edge_z, dim3(2048), dim3(256), 0, stream,
                           edge_index, coord, edge_attr, Cr, Cea, Wc2, vWc1h, Z);
        hipLaunchKernelGGL(k_node_main, dim3(N_ / 4), dim3(256), 0, stream,
                           edge_index, offsets, edge_ids, alpha, v_h, Z, coord, edge_attr, h,
                           Wkv, h_out, coord_out, att_out);
    } else {
        // ---- slow validated path (separate layout from offset 0)
        off = 0;
        float* s        = (float*)alloc((size_t)N_ * 4);
        unsigned int* m = (unsigned int*)alloc((size_t)N_ * 4);
        float* agg      = (float*)alloc((size_t)N_ * 128 * 4);
        float* cagg     = (float*)alloc((size_t)N_ * 12 * 4);
        size_t zb       = off;
        float* hq2      = (float*)alloc((size_t)N_ * 128 * 4);
        float* alpha2   = (float*)alloc((size_t)E_ * 4);
        int zero_n = (int)(zb / 4);
        hipLaunchKernelGGL(k_zero, dim3((zero_n + 255) / 256), dim3(256), 0, stream,
                           (unsigned int*)s, zero_n);
        hipLaunchKernelGGL(k_hq_slow, dim3(N_ * 128 / 256), dim3(256), 0, stream, h, Wq, bq, hq2);
        hipLaunchKernelGGL(k_alpha_slow, dim3(E_ / 4), dim3(256), 0, stream,
                           edge_index, coord, edge_attr, h, Wkv, bkv, hq2, alpha2, m);
        hipLaunchKernelGGL(k_expsum_slow, dim3((E_ + 255) / 256), dim3(256), 0, stream,
                           edge_index, alpha2, m, s);
        hipLaunchKernelGGL(k_edge2_slow, dim3(E_ / 4), dim3(256), 0, stream,
                           edge_index, coord, edge_attr, h, Wkv, bkv, Wc1, Wc2,
                           alpha2, m, s, agg, cagg, att_out);
        hipLaunchKernelGGL(k_final_slow, dim3(N_ * 128 / 256), dim3(256), 0, stream,
                           h, coord, agg, cagg, h_out, coord_out);
    }
}

// Round 7
// 1348.136 us; speedup vs baseline: 7.5968x; 3.8387x over previous
//
#include <hip/hip_runtime.h>

typedef unsigned short u16;

constexpr int N_ = 20000;
constexpr int E_ = 400000;

#define DEV __device__ __forceinline__

DEV float bf2f(u16 u) { union { unsigned int i; float f; } x; x.i = ((unsigned int)u) << 16; return x.f; }
DEV u16 f2bf(float f) {
    union { unsigned int i; float f; } x; x.f = f;
    unsigned int i = x.i;
    unsigned int r = i + 0x7FFFu + ((i >> 16) & 1u);
    return (u16)(r >> 16);
}
// order-preserving float<->uint for atomicMax (unsigned) [slow path only]
DEV unsigned int fenc(float f) {
    unsigned int i = __float_as_uint(f);
    return (i & 0x80000000u) ? ~i : (i | 0x80000000u);
}
DEV float fdec(unsigned int u) {
    return (u & 0x80000000u) ? __uint_as_float(u ^ 0x80000000u) : __uint_as_float(~u);
}

// ---------------------------------------------------------------- zero a uint span
__global__ __launch_bounds__(256) void k_zero(unsigned int* p, int n) {
    int i = blockIdx.x * 256 + threadIdx.x;
    if (i < n) p[i] = 0u;
}

// ================================================================ FAST PATH
// ---------------------------------------------------------------- per-node hq / k_h / v_h (8 nodes per block)
__global__ __launch_bounds__(256) void k_node1(
    const float* __restrict__ h, const float* __restrict__ Wq, const float* __restrict__ bq,
    const float* __restrict__ Wkv, const float* __restrict__ bkv,
    float* __restrict__ hq, float* __restrict__ k_h, float* __restrict__ v_h) {
    __shared__ float hl[8][128];
    int t = threadIdx.x;
    int node0 = blockIdx.x * 8;
    for (int u = t; u < 1024; u += 256) hl[u >> 7][u & 127] = h[(size_t)(node0 + (u >> 7)) * 128 + (u & 127)];
    __syncthreads();
    int d = t & 127, half = t >> 7;
    float aq[4] = {0, 0, 0, 0}, ak[4] = {0, 0, 0, 0}, av[4] = {0, 0, 0, 0};
    for (int k = 0; k < 128; ++k) {
        float wq = Wq[k * 128 + d];
        float2 wkv = *(const float2*)(Wkv + (size_t)(16 + k) * 256 + 2 * d);
#pragma unroll
        for (int i = 0; i < 4; ++i) {
            float hv = hl[half * 4 + i][k];
            aq[i] += hv * wq;
            ak[i] += hv * wkv.x;
            av[i] += hv * wkv.y;
        }
    }
    float bqd = bq[d], bk = bkv[2 * d], bv = bkv[2 * d + 1];
#pragma unroll
    for (int i = 0; i < 4; ++i) {
        size_t o = (size_t)(node0 + half * 4 + i) * 128 + d;
        hq[o] = aq[i] + bqd;
        k_h[o] = ak[i] + bk;
        v_h[o] = av[i] + bv;
    }
}

// ---------------------------------------------------------------- composites Cr/Cea (32 x 512)
__global__ __launch_bounds__(256) void k_composites(
    const float* __restrict__ Wkv, const float* __restrict__ Wc1,
    float* __restrict__ Cr, float* __restrict__ Cea) {
    int o = blockIdx.x * 256 + threadIdx.x;   // 16384 exact
    int half = o >> 13;
    int j = (o >> 9) & 15;
    int jc = o & 511;
    int row = half ? (144 + j) : j;
    float acc = 0.f;
    for (int d = 0; d < 128; ++d)
        acc += Wkv[(size_t)row * 256 + 2 * d + 1] * Wc1[(size_t)d * 512 + jc];
    (half ? Cea : Cr)[j * 512 + jc] = acc;
}

// ---------------------------------------------------------------- hqWkr / hqWkea (N x 16 each)
__global__ __launch_bounds__(256) void k_hqw(
    const float* __restrict__ hq, const float* __restrict__ Wkv,
    float* __restrict__ hqWkr, float* __restrict__ hqWkea) {
    int idx = blockIdx.x * 256 + threadIdx.x;   // N*32 exact
    int n = idx >> 5, j5 = idx & 31;
    int j = j5 & 15;
    int wrow = (j5 < 16) ? j : (144 + j);
    float acc = 0.f;
    for (int d = 0; d < 128; ++d) acc += hq[(size_t)n * 128 + d] * Wkv[(size_t)wrow * 256 + 2 * d];
    ((j5 < 16) ? hqWkr : hqWkea)[(size_t)n * 16 + j] = acc;
}

// ---------------------------------------------------------------- vWc1h[n][jc] = (v_h[n] @ Wc1)[jc], bf16 (8 nodes/block)
__global__ __launch_bounds__(256) void k_vwc1(
    const float* __restrict__ v_h, const float* __restrict__ Wc1, u16* __restrict__ vWc1h) {
    __shared__ float vl[8][128];
    int t = threadIdx.x;
    int node0 = blockIdx.x * 8;
    for (int u = t; u < 1024; u += 256) vl[u >> 7][u & 127] = v_h[(size_t)(node0 + (u >> 7)) * 128 + (u & 127)];
    __syncthreads();
    for (int g = 0; g < 2; ++g) {
        int jc = g * 256 + t;
        float acc[8] = {0, 0, 0, 0, 0, 0, 0, 0};
        for (int dd = 0; dd < 128; ++dd) {
            float w = Wc1[(size_t)dd * 512 + jc];
#pragma unroll
            for (int n = 0; n < 8; ++n) acc[n] += vl[n][dd] * w;
        }
#pragma unroll
        for (int n = 0; n < 8; ++n) vWc1h[(size_t)(node0 + n) * 512 + jc] = f2bf(acc[n]);
    }
}

// ---------------------------------------------------------------- alpha (decomposed) + degree histogram
__global__ __launch_bounds__(256) void k_alpha_fast(
    const int* __restrict__ edge_index, const float* __restrict__ coord,
    const float* __restrict__ edge_attr,
    const float* __restrict__ hq, const float* __restrict__ k_h,
    const float* __restrict__ hqWkr, const float* __restrict__ hqWkea,
    float* __restrict__ alpha, int* __restrict__ counts) {
    int wv = threadIdx.x >> 6, lane = threadIdx.x & 63;
    int e = blockIdx.x * 4 + wv;
    int row = edge_index[e], col = edge_index[E_ + e];
    float p = hq[(size_t)row * 128 + lane] * k_h[(size_t)col * 128 + lane] +
              hq[(size_t)row * 128 + 64 + lane] * k_h[(size_t)col * 128 + 64 + lane];
    if (lane < 16) {
        int c = lane >> 2, f = lane & 3;
        float rj = 0.f;
#pragma unroll
        for (int x = 0; x < 3; ++x) {
            float a = coord[(size_t)row * 12 + c * 3 + x] - coord[(size_t)col * 12 + c * 3 + x];
            float b = coord[(size_t)row * 12 + f * 3 + x] - coord[(size_t)col * 12 + f * 3 + x];
            rj += a * b;
        }
        p += hqWkr[(size_t)row * 16 + lane] * rj;
    } else if (lane < 32) {
        int j = lane - 16;
        p += hqWkea[(size_t)row * 16 + j] * edge_attr[(size_t)e * 16 + j];
    }
#pragma unroll
    for (int mm = 32; mm; mm >>= 1) p += __shfl_xor(p, mm);
    if (lane == 0) {
        alpha[e] = p;
        atomicAdd(&counts[row], 1);
    }
}

// ---------------------------------------------------------------- exclusive scan (single block, wave scans)
__global__ __launch_bounds__(1024) void k_scan(const int* __restrict__ counts,
                                               int* __restrict__ offsets, int* __restrict__ cursor) {
    __shared__ int wtot[16];
    int t = threadIdx.x;
    int lane = t & 63, wv = t >> 6;
    int base = 0;
    for (int start = 0; start < N_; start += 1024) {
        int i = start + t;
        int orig = (i < N_) ? counts[i] : 0;
        int v = orig;
#pragma unroll
        for (int off = 1; off < 64; off <<= 1) {
            int x = __shfl_up(v, off);
            if (lane >= off) v += x;
        }
        if (lane == 63) wtot[wv] = v;
        __syncthreads();
        int wbase = 0, chunktot = 0;
#pragma unroll
        for (int k = 0; k < 16; ++k) {
            int wt = wtot[k];
            if (k < wv) wbase += wt;
            chunktot += wt;
        }
        if (i < N_) {
            int excl = base + wbase + v - orig;
            offsets[i] = excl;
            cursor[i] = excl;
        }
        base += chunktot;
        __syncthreads();
    }
    if (t == 0) offsets[N_] = base;
}

// ---------------------------------------------------------------- CSR fill
__global__ void k_fill(const int* __restrict__ edge_index, int* __restrict__ cursor,
                       int* __restrict__ edge_ids) {
    int i = blockIdx.x * 256 + threadIdx.x;
    if (i < E_) {
        int r = edge_index[i];
        int pos = atomicAdd(&cursor[r], 1);
        edge_ids[pos] = i;
    }
}

// ---------------------------------------------------------------- per-edge Z[e][4] = silu(u) @ Wc2
// 1 edge per wave; Ccomb packed bf16 in 32 KB LDS; VGPR capped at 128 (4 waves/EU)
__global__ __launch_bounds__(256, 4) void k_edge_z(
    const int* __restrict__ edge_index, const float* __restrict__ coord,
    const float* __restrict__ edge_attr,
    const float* __restrict__ Cr, const float* __restrict__ Cea, const float* __restrict__ Wc2,
    const u16* __restrict__ vWc1h, float* __restrict__ Z) {
    __shared__ unsigned int CcP[32 * 256];  // 32 KB: word j*256+jc' = bf16(Cc[j][jc']) | bf16(Cc[j][jc'+256])<<16
    __shared__ float W2t[4 * 512];          // 8 KB transposed Wc2
    int t = threadIdx.x;
    for (int i = t; i < 8192; i += 256) {
        int j = i >> 8, jc = i & 255;
        const float* src = (j < 16) ? (Cr + (size_t)j * 512) : (Cea + (size_t)(j - 16) * 512);
        unsigned int lo = (unsigned int)f2bf(src[jc]);
        unsigned int hi = (unsigned int)f2bf(src[jc + 256]);
        CcP[i] = lo | (hi << 16);
    }
    for (int i = t; i < 2048; i += 256) W2t[(i & 3) * 512 + (i >> 2)] = Wc2[i];
    __syncthreads();
    int wv = t >> 6, lane = t & 63;
    int w = blockIdx.x * 4 + wv;
    int wstride = gridDim.x * 4;
    for (int e = w; e < E_; e += wstride) {
        int row = edge_index[e], col = edge_index[E_ + e];
        // coord diff in lanes 0..11, broadcast via shuffles
        float d = 0.f;
        if (lane < 12) d = coord[(size_t)row * 12 + lane] - coord[(size_t)col * 12 + lane];
        // X: lane<16 -> radial[(lane>>2)][(lane&3)], lanes 16..31 -> edge_attr, else 0
        float X = 0.f;
        {
            int c3 = (lane >> 2) * 3, f3 = (lane & 3) * 3;
            float r = 0.f;
#pragma unroll
            for (int x = 0; x < 3; ++x) r += __shfl(d, c3 + x) * __shfl(d, f3 + x);
            if (lane < 16) X = r;
            else if (lane < 32) X = edge_attr[(size_t)e * 16 + lane - 16];
        }
        // u init from vWc1h[col] gather (coalesced u16 loads)
        float ulo[4], uhi[4];
#pragma unroll
        for (int g = 0; g < 4; ++g) {
            int jc = g * 64 + lane;
            ulo[g] = bf2f(vWc1h[(size_t)col * 512 + jc]);
            uhi[g] = bf2f(vWc1h[(size_t)col * 512 + 256 + jc]);
        }
        // u += X @ Ccomb  (broadcast X_j via shuffle, packed bf16 LDS reads)
#pragma unroll 8
        for (int j = 0; j < 32; ++j) {
            float xj = __shfl(X, j);
#pragma unroll
            for (int g = 0; g < 4; ++g) {
                unsigned int p = CcP[j * 256 + g * 64 + lane];
                float clo = __uint_as_float(p << 16);
                float chi = __uint_as_float(p & 0xFFFF0000u);
                ulo[g] += xj * clo;
                uhi[g] += xj * chi;
            }
        }
        // silu + @Wc2 partials, then wave reduction
        float cv[4] = {0.f, 0.f, 0.f, 0.f};
#pragma unroll
        for (int g = 0; g < 4; ++g) {
            int jc = g * 64 + lane;
            float s0 = ulo[g] / (1.f + __expf(-ulo[g]));
            float s1 = uhi[g] / (1.f + __expf(-uhi[g]));
#pragma unroll
            for (int c = 0; c < 4; ++c)
                cv[c] += s0 * W2t[c * 512 + jc] + s1 * W2t[c * 512 + 256 + jc];
        }
#pragma unroll
        for (int mm = 32; mm; mm >>= 1)
#pragma unroll
            for (int c = 0; c < 4; ++c) cv[c] += __shfl_xor(cv[c], mm);
        if (lane < 4) Z[(size_t)e * 4 + lane] = cv[lane];
    }
}

// ---------------------------------------------------------------- per-node softmax + all aggregations (no atomics)
__global__ __launch_bounds__(256) void k_node_main(
    const int* __restrict__ edge_index, const int* __restrict__ offsets, const int* __restrict__ edge_ids,
    const float* __restrict__ alpha, const float* __restrict__ v_h, const float* __restrict__ Z,
    const float* __restrict__ coord, const float* __restrict__ edge_attr, const float* __restrict__ h,
    const float* __restrict__ Wkv, float* __restrict__ h_out, float* __restrict__ coord_out,
    float* __restrict__ att_out) {
    int wv = threadIdx.x >> 6, lane = threadIdx.x & 63;
    int n = blockIdx.x * 4 + wv;
    int beg = offsets[n], end = offsets[n + 1];
    float cn[12];
#pragma unroll
    for (int i = 0; i < 12; ++i) cn[i] = coord[(size_t)n * 12 + i];
    // softmax max
    float mloc = -3.402823466e38f;
    for (int i = beg + lane; i < end; i += 64) mloc = fmaxf(mloc, alpha[edge_ids[i]]);
#pragma unroll
    for (int mm = 32; mm; mm >>= 1) mloc = fmaxf(mloc, __shfl_xor(mloc, mm));
    // softmax sum
    float sloc = 0.f;
    for (int i = beg + lane; i < end; i += 64) sloc += __expf(alpha[edge_ids[i]] - mloc);
#pragma unroll
    for (int mm = 32; mm; mm >>= 1) sloc += __shfl_xor(sloc, mm);
    float inv_s = (end > beg) ? 1.f / sloc : 0.f;
    // lane-parallel pass
    float raggr[16], eaggr[16], cagg[12];
#pragma unroll
    for (int j = 0; j < 16; ++j) { raggr[j] = 0.f; eaggr[j] = 0.f; }
#pragma unroll
    for (int j = 0; j < 12; ++j) cagg[j] = 0.f;
    for (int i = beg + lane; i < end; i += 64) {
        int e = edge_ids[i];
        int col = edge_index[E_ + e];
        float att = __expf(alpha[e] - mloc) * inv_s;
        att_out[e] = att;
        float cd[12];
#pragma unroll
        for (int x = 0; x < 12; ++x) cd[x] = cn[x] - coord[(size_t)col * 12 + x];
#pragma unroll
        for (int c = 0; c < 4; ++c)
#pragma unroll
            for (int f = 0; f < 4; ++f) {
                float r = cd[c * 3] * cd[f * 3] + cd[c * 3 + 1] * cd[f * 3 + 1] + cd[c * 3 + 2] * cd[f * 3 + 2];
                raggr[c * 4 + f] += att * r;
            }
#pragma unroll
        for (int j = 0; j < 16; ++j) eaggr[j] += att * edge_attr[(size_t)e * 16 + j];
        float cv0 = att * Z[(size_t)e * 4 + 0];
        float cv1 = att * Z[(size_t)e * 4 + 1];
        float cv2 = att * Z[(size_t)e * 4 + 2];
        float cv3 = att * Z[(size_t)e * 4 + 3];
#pragma unroll
        for (int x = 0; x < 3; ++x) {
            cagg[0 + x] += cv0 * cd[0 + x];
            cagg[3 + x] += cv1 * cd[3 + x];
            cagg[6 + x] += cv2 * cd[6 + x];
            cagg[9 + x] += cv3 * cd[9 + x];
        }
    }
#pragma unroll
    for (int mm = 32; mm; mm >>= 1) {
#pragma unroll
        for (int j = 0; j < 16; ++j) {
            raggr[j] += __shfl_xor(raggr[j], mm);
            eaggr[j] += __shfl_xor(eaggr[j], mm);
        }
#pragma unroll
        for (int j = 0; j < 12; ++j) cagg[j] += __shfl_xor(cagg[j], mm);
    }
    // wave-cooperative agg (128-dim)
    float agg0 = 0.f, agg1 = 0.f;
    for (int i = beg; i < end; ++i) {
        int e = edge_ids[i];
        int col = edge_index[E_ + e];
        float att = __expf(alpha[e] - mloc) * inv_s;
        agg0 += att * v_h[(size_t)col * 128 + lane];
        agg1 += att * v_h[(size_t)col * 128 + 64 + lane];
    }
#pragma unroll
    for (int g = 0; g < 2; ++g) {
        int dd = g * 64 + lane;
        float acc = g ? agg1 : agg0;
#pragma unroll
        for (int j = 0; j < 16; ++j) {
            acc += raggr[j] * Wkv[(size_t)j * 256 + 2 * dd + 1];
            acc += eaggr[j] * Wkv[(size_t)(144 + j) * 256 + 2 * dd + 1];
        }
        h_out[(size_t)n * 128 + dd] = h[(size_t)n * 128 + dd] + acc;
    }
    if (lane == 0) {
#pragma unroll
        for (int i = 0; i < 12; ++i) {
            float v = fminf(fmaxf(cagg[i], -10.f), 10.f);
            coord_out[(size_t)n * 12 + i] = cn[i] + v;
        }
    }
}

// ================================================================ SLOW (validated) FALLBACK PATH
__global__ __launch_bounds__(256) void k_hq_slow(
    const float* __restrict__ h, const float* __restrict__ Wq, const float* __restrict__ bq,
    float* __restrict__ hq) {
    int idx = blockIdx.x * 256 + threadIdx.x;
    int n = idx >> 7, d = idx & 127;
    float acc = 0.f;
    for (int k = 0; k < 128; ++k) acc += h[(size_t)n * 128 + k] * Wq[k * 128 + d];
    hq[idx] = acc + bq[d];
}

__global__ __launch_bounds__(256) void k_alpha_slow(
    const int* __restrict__ edge_index, const float* __restrict__ coord,
    const float* __restrict__ edge_attr, const float* __restrict__ h,
    const float* __restrict__ Wkv, const float* __restrict__ bkv,
    const float* __restrict__ hq, float* __restrict__ alpha, unsigned int* __restrict__ m) {
    __shared__ float tf[4][160];
    int wv = threadIdx.x >> 6, lane = threadIdx.x & 63;
    int e = blockIdx.x * 4 + wv;
    int row = edge_index[e], col = edge_index[E_ + e];
    if (lane < 16) {
        int c = lane >> 2, f = lane & 3;
        float rj = 0.f;
#pragma unroll
        for (int x = 0; x < 3; ++x) {
            float a = coord[(size_t)row * 12 + c * 3 + x] - coord[(size_t)col * 12 + c * 3 + x];
            float b = coord[(size_t)row * 12 + f * 3 + x] - coord[(size_t)col * 12 + f * 3 + x];
            rj += a * b;
        }
        tf[wv][lane] = rj;
    }
    for (int f = lane; f < 128; f += 64) tf[wv][16 + f] = h[(size_t)col * 128 + f];
    if (lane >= 48) tf[wv][144 + lane - 48] = edge_attr[(size_t)e * 16 + lane - 48];
    __syncthreads();
    float k0 = bkv[2 * lane], k1 = bkv[2 * (64 + lane)];
    for (int f = 0; f < 160; ++f) {
        float tfv = tf[wv][f];
        k0 += tfv * Wkv[f * 256 + 2 * lane];
        k1 += tfv * Wkv[f * 256 + 128 + 2 * lane];
    }
    float p = hq[(size_t)row * 128 + lane] * k0 + hq[(size_t)row * 128 + 64 + lane] * k1;
#pragma unroll
    for (int mm = 32; mm; mm >>= 1) p += __shfl_xor(p, mm);
    if (lane == 0) {
        alpha[e] = p;
        atomicMax(&m[row], fenc(p));
    }
}

__global__ __launch_bounds__(256) void k_expsum_slow(
    const int* __restrict__ edge_index, const float* __restrict__ alpha,
    const unsigned int* __restrict__ m, float* __restrict__ s) {
    int e = blockIdx.x * 256 + threadIdx.x;
    if (e < E_) {
        int row = edge_index[e];
        atomicAdd(&s[row], __expf(alpha[e] - fdec(m[row])));
    }
}

__global__ __launch_bounds__(256) void k_edge2_slow(
    const int* __restrict__ edge_index, const float* __restrict__ coord,
    const float* __restrict__ edge_attr, const float* __restrict__ h,
    const float* __restrict__ Wkv, const float* __restrict__ bkv,
    const float* __restrict__ Wc1, const float* __restrict__ Wc2,
    const float* __restrict__ alpha, const unsigned int* __restrict__ m, const float* __restrict__ s,
    float* __restrict__ agg, float* __restrict__ cagg, float* __restrict__ att_out) {
    __shared__ float tf[4][160];
    __shared__ float vsh[4][128];
    int wv = threadIdx.x >> 6, lane = threadIdx.x & 63;
    int e = blockIdx.x * 4 + wv;
    int row = edge_index[e], col = edge_index[E_ + e];
    if (lane < 16) {
        int c = lane >> 2, f = lane & 3;
        float rj = 0.f;
#pragma unroll
        for (int x = 0; x < 3; ++x) {
            float a = coord[(size_t)row * 12 + c * 3 + x] - coord[(size_t)col * 12 + c * 3 + x];
            float b = coord[(size_t)row * 12 + f * 3 + x] - coord[(size_t)col * 12 + f * 3 + x];
            rj += a * b;
        }
        tf[wv][lane] = rj;
    }
    for (int f = lane; f < 128; f += 64) tf[wv][16 + f] = h[(size_t)col * 128 + f];
    if (lane >= 48) tf[wv][144 + lane - 48] = edge_attr[(size_t)e * 16 + lane - 48];
    __syncthreads();
    float v0 = bkv[2 * lane + 1], v1 = bkv[2 * (64 + lane) + 1];
    for (int f = 0; f < 160; ++f) {
        float tfv = tf[wv][f];
        v0 += tfv * Wkv[f * 256 + 2 * lane + 1];
        v1 += tfv * Wkv[f * 256 + 129 + 2 * lane];
    }
    float att = __expf(alpha[e] - fdec(m[row])) / s[row];
    atomicAdd(&agg[(size_t)row * 128 + lane], att * v0);
    atomicAdd(&agg[(size_t)row * 128 + 64 + lane], att * v1);
    vsh[wv][lane] = v0;
    vsh[wv][64 + lane] = v1;
    __syncthreads();
    float cv[4] = {0.f, 0.f, 0.f, 0.f};
    for (int g = 0; g < 8; ++g) {
        int jc = g * 64 + lane;
        float u = 0.f;
        for (int dd = 0; dd < 128; ++dd) u += vsh[wv][dd] * Wc1[dd * 512 + jc];
        float su = u / (1.f + __expf(-u));
#pragma unroll
        for (int c = 0; c < 4; ++c) cv[c] += su * Wc2[jc * 4 + c];
    }
#pragma unroll
    for (int mm = 32; mm; mm >>= 1)
#pragma unroll
        for (int c = 0; c < 4; ++c) cv[c] += __shfl_xor(cv[c], mm);
    if (lane < 12) {
        int c = lane / 3;
        float cd = coord[(size_t)row * 12 + lane] - coord[(size_t)col * 12 + lane];
        atomicAdd(&cagg[(size_t)row * 12 + lane], att * cv[c] * cd);
    }
    if (lane == 0) att_out[e] = att;
}

__global__ __launch_bounds__(256) void k_final_slow(
    const float* __restrict__ h, const float* __restrict__ coord,
    const float* __restrict__ agg, const float* __restrict__ cagg,
    float* __restrict__ h_out, float* __restrict__ coord_out) {
    int idx = blockIdx.x * 256 + threadIdx.x;
    h_out[idx] = h[idx] + agg[idx];
    if (idx < N_ * 12) {
        float v = fminf(fmaxf(cagg[idx], -10.f), 10.f);
        coord_out[idx] = coord[idx] + v;
    }
}

// ---------------------------------------------------------------- launch
extern "C" void kernel_launch(void* const* d_in, const int* in_sizes, int n_in,
                              void* d_out, int out_size, void* d_ws, size_t ws_size,
                              hipStream_t stream) {
    (void)in_sizes; (void)n_in; (void)out_size;
    const float* h          = (const float*)d_in[0];
    const float* coord      = (const float*)d_in[1];
    const int*   edge_index = (const int*)d_in[2];
    const float* edge_attr  = (const float*)d_in[3];
    const float* Wq         = (const float*)d_in[4];
    const float* bq         = (const float*)d_in[5];
    const float* Wkv        = (const float*)d_in[6];
    const float* bkv        = (const float*)d_in[7];
    const float* Wc1        = (const float*)d_in[8];
    const float* Wc2        = (const float*)d_in[9];

    float* out = (float*)d_out;
    float* h_out = out;
    float* coord_out = out + (size_t)N_ * 128;
    float* att_out = coord_out + (size_t)N_ * 12;

    char* w = (char*)d_ws;
    size_t off = 0;
    auto alloc = [&](size_t bytes) -> void* {
        void* p = w + off;
        off += (bytes + 255) & ~(size_t)255;
        return p;
    };
    // ---- fast-path layout
    int* counts   = (int*)alloc((size_t)N_ * 4);          // zeroed
    float* hq     = (float*)alloc((size_t)N_ * 128 * 4);
    float* k_h    = (float*)alloc((size_t)N_ * 128 * 4);
    float* v_h    = (float*)alloc((size_t)N_ * 128 * 4);
    u16*   vWc1h  = (u16*)alloc((size_t)N_ * 512 * 2);
    float* hqWkr  = (float*)alloc((size_t)N_ * 16 * 4);
    float* hqWkea = (float*)alloc((size_t)N_ * 16 * 4);
    float* alpha  = (float*)alloc((size_t)E_ * 4);
    float* Z      = (float*)alloc((size_t)E_ * 4 * 4);
    float* Cr     = (float*)alloc(16 * 512 * 4);
    float* Cea    = (float*)alloc(16 * 512 * 4);
    int* offsets  = (int*)alloc((size_t)(N_ + 1) * 4);
    int* cursor   = (int*)alloc((size_t)N_ * 4);
    int* edge_ids = (int*)alloc((size_t)E_ * 4);
    size_t fast_req = off;

    if (ws_size >= fast_req) {
        hipLaunchKernelGGL(k_zero, dim3((N_ + 255) / 256), dim3(256), 0, stream,
                           (unsigned int*)counts, N_);
        hipLaunchKernelGGL(k_node1, dim3(N_ / 8), dim3(256), 0, stream,
                           h, Wq, bq, Wkv, bkv, hq, k_h, v_h);
        hipLaunchKernelGGL(k_composites, dim3(64), dim3(256), 0, stream, Wkv, Wc1, Cr, Cea);
        hipLaunchKernelGGL(k_hqw, dim3(N_ * 32 / 256), dim3(256), 0, stream, hq, Wkv, hqWkr, hqWkea);
        hipLaunchKernelGGL(k_vwc1, dim3(N_ / 8), dim3(256), 0, stream, v_h, Wc1, vWc1h);
        hipLaunchKernelGGL(k_alpha_fast, dim3(E_ / 4), dim3(256), 0, stream,
                           edge_index, coord, edge_attr, hq, k_h, hqWkr, hqWkea, alpha, counts);
        hipLaunchKernelGGL(k_scan, dim3(1), dim3(1024), 0, stream, counts, offsets, cursor);
        hipLaunchKernelGGL(k_fill, dim3((E_ + 255) / 256), dim3(256), 0, stream,
                           edge_index, cursor, edge_ids);
        hipLaunchKernelGGL(k_edge_z, dim3(2048), dim3(256), 0, stream,
                           edge_index, coord, edge_attr, Cr, Cea, Wc2, vWc1h, Z);
        hipLaunchKernelGGL(k_node_main, dim3(N_ / 4), dim3(256), 0, stream,
                           edge_index, offsets, edge_ids, alpha, v_h, Z, coord, edge_attr, h,
                           Wkv, h_out, coord_out, att_out);
    } else {
        // ---- slow validated path (separate layout from offset 0)
        off = 0;
        float* s        = (float*)alloc((size_t)N_ * 4);
        unsigned int* m = (unsigned int*)alloc((size_t)N_ * 4);
        float* agg      = (float*)alloc((size_t)N_ * 128 * 4);
        float* cagg     = (float*)alloc((size_t)N_ * 12 * 4);
        size_t zb       = off;
        float* hq2      = (float*)alloc((size_t)N_ * 128 * 4);
        float* alpha2   = (float*)alloc((size_t)E_ * 4);
        int zero_n = (int)(zb / 4);
        hipLaunchKernelGGL(k_zero, dim3((zero_n + 255) / 256), dim3(256), 0, stream,
                           (unsigned int*)s, zero_n);
        hipLaunchKernelGGL(k_hq_slow, dim3(N_ * 128 / 256), dim3(256), 0, stream, h, Wq, bq, hq2);
        hipLaunchKernelGGL(k_alpha_slow, dim3(E_ / 4), dim3(256), 0, stream,
                           edge_index, coord, edge_attr, h, Wkv, bkv, hq2, alpha2, m);
        hipLaunchKernelGGL(k_expsum_slow, dim3((E_ + 255) / 256), dim3(256), 0, stream,
                           edge_index, alpha2, m, s);
        hipLaunchKernelGGL(k_edge2_slow, dim3(E_ / 4), dim3(256), 0, stream,
                           edge_index, coord, edge_attr, h, Wkv, bkv, Wc1, Wc2,
                           alpha2, m, s, agg, cagg, att_out);
        hipLaunchKernelGGL(k_final_slow, dim3(N_ * 128 / 256), dim3(256), 0, stream,
                           h, coord, agg, cagg, h_out, coord_out);
    }
}

// Round 8
// 955.979 us; speedup vs baseline: 10.7131x; 1.4102x over previous
//
#include <hip/hip_runtime.h>

typedef unsigned short u16;
typedef __attribute__((ext_vector_type(8))) short short8;
typedef __attribute__((ext_vector_type(4))) float floatx4;

constexpr int N_ = 20000;
constexpr int E_ = 400000;

#define DEV __device__ __forceinline__

DEV float bf2f(u16 u) { union { unsigned int i; float f; } x; x.i = ((unsigned int)u) << 16; return x.f; }
DEV u16 f2bf(float f) {
    union { unsigned int i; float f; } x; x.f = f;
    unsigned int i = x.i;
    unsigned int r = i + 0x7FFFu + ((i >> 16) & 1u);
    return (u16)(r >> 16);
}
// order-preserving float<->uint for atomicMax (unsigned) [slow path only]
DEV unsigned int fenc(float f) {
    unsigned int i = __float_as_uint(f);
    return (i & 0x80000000u) ? ~i : (i | 0x80000000u);
}
DEV float fdec(unsigned int u) {
    return (u & 0x80000000u) ? __uint_as_float(u ^ 0x80000000u) : __uint_as_float(~u);
}

// ---------------------------------------------------------------- zero a uint span
__global__ __launch_bounds__(256) void k_zero(unsigned int* p, int n) {
    int i = blockIdx.x * 256 + threadIdx.x;
    if (i < n) p[i] = 0u;
}

// ================================================================ FAST PATH
// ---------------------------------------------------------------- per-node hq / k_h / v_h (8 nodes per block)
__global__ __launch_bounds__(256) void k_node1(
    const float* __restrict__ h, const float* __restrict__ Wq, const float* __restrict__ bq,
    const float* __restrict__ Wkv, const float* __restrict__ bkv,
    float* __restrict__ hq, float* __restrict__ k_h, float* __restrict__ v_h) {
    __shared__ float hl[8][128];
    int t = threadIdx.x;
    int node0 = blockIdx.x * 8;
    for (int u = t; u < 1024; u += 256) hl[u >> 7][u & 127] = h[(size_t)(node0 + (u >> 7)) * 128 + (u & 127)];
    __syncthreads();
    int d = t & 127, half = t >> 7;
    float aq[4] = {0, 0, 0, 0}, ak[4] = {0, 0, 0, 0}, av[4] = {0, 0, 0, 0};
    for (int k = 0; k < 128; ++k) {
        float wq = Wq[k * 128 + d];
        float2 wkv = *(const float2*)(Wkv + (size_t)(16 + k) * 256 + 2 * d);
#pragma unroll
        for (int i = 0; i < 4; ++i) {
            float hv = hl[half * 4 + i][k];
            aq[i] += hv * wq;
            ak[i] += hv * wkv.x;
            av[i] += hv * wkv.y;
        }
    }
    float bqd = bq[d], bk = bkv[2 * d], bv = bkv[2 * d + 1];
#pragma unroll
    for (int i = 0; i < 4; ++i) {
        size_t o = (size_t)(node0 + half * 4 + i) * 128 + d;
        hq[o] = aq[i] + bqd;
        k_h[o] = ak[i] + bk;
        v_h[o] = av[i] + bv;
    }
}

// ---------------------------------------------------------------- composites Cr/Cea (32 x 512)
__global__ __launch_bounds__(256) void k_composites(
    const float* __restrict__ Wkv, const float* __restrict__ Wc1,
    float* __restrict__ Cr, float* __restrict__ Cea) {
    int o = blockIdx.x * 256 + threadIdx.x;   // 16384 exact
    int half = o >> 13;
    int j = (o >> 9) & 15;
    int jc = o & 511;
    int row = half ? (144 + j) : j;
    float acc = 0.f;
    for (int d = 0; d < 128; ++d)
        acc += Wkv[(size_t)row * 256 + 2 * d + 1] * Wc1[(size_t)d * 512 + jc];
    (half ? Cea : Cr)[j * 512 + jc] = acc;
}

// ---------------------------------------------------------------- hqWkr / hqWkea (N x 16 each)
__global__ __launch_bounds__(256) void k_hqw(
    const float* __restrict__ hq, const float* __restrict__ Wkv,
    float* __restrict__ hqWkr, float* __restrict__ hqWkea) {
    int idx = blockIdx.x * 256 + threadIdx.x;   // N*32 exact
    int n = idx >> 5, j5 = idx & 31;
    int j = j5 & 15;
    int wrow = (j5 < 16) ? j : (144 + j);
    float acc = 0.f;
    for (int d = 0; d < 128; ++d) acc += hq[(size_t)n * 128 + d] * Wkv[(size_t)wrow * 256 + 2 * d];
    ((j5 < 16) ? hqWkr : hqWkea)[(size_t)n * 16 + j] = acc;
}

// ---------------------------------------------------------------- vWc1h[n][jc] = (v_h[n] @ Wc1)[jc], bf16 (8 nodes/block)
__global__ __launch_bounds__(256) void k_vwc1(
    const float* __restrict__ v_h, const float* __restrict__ Wc1, u16* __restrict__ vWc1h) {
    __shared__ float vl[8][128];
    int t = threadIdx.x;
    int node0 = blockIdx.x * 8;
    for (int u = t; u < 1024; u += 256) vl[u >> 7][u & 127] = v_h[(size_t)(node0 + (u >> 7)) * 128 + (u & 127)];
    __syncthreads();
    for (int g = 0; g < 2; ++g) {
        int jc = g * 256 + t;
        float acc[8] = {0, 0, 0, 0, 0, 0, 0, 0};
        for (int dd = 0; dd < 128; ++dd) {
            float w = Wc1[(size_t)dd * 512 + jc];
#pragma unroll
            for (int n = 0; n < 8; ++n) acc[n] += vl[n][dd] * w;
        }
#pragma unroll
        for (int n = 0; n < 8; ++n) vWc1h[(size_t)(node0 + n) * 512 + jc] = f2bf(acc[n]);
    }
}

// ---------------------------------------------------------------- alpha (decomposed) + degree histogram
__global__ __launch_bounds__(256) void k_alpha_fast(
    const int* __restrict__ edge_index, const float* __restrict__ coord,
    const float* __restrict__ edge_attr,
    const float* __restrict__ hq, const float* __restrict__ k_h,
    const float* __restrict__ hqWkr, const float* __restrict__ hqWkea,
    float* __restrict__ alpha, int* __restrict__ counts) {
    int wv = threadIdx.x >> 6, lane = threadIdx.x & 63;
    int e = blockIdx.x * 4 + wv;
    int row = edge_index[e], col = edge_index[E_ + e];
    float p = hq[(size_t)row * 128 + lane] * k_h[(size_t)col * 128 + lane] +
              hq[(size_t)row * 128 + 64 + lane] * k_h[(size_t)col * 128 + 64 + lane];
    if (lane < 16) {
        int c = lane >> 2, f = lane & 3;
        float rj = 0.f;
#pragma unroll
        for (int x = 0; x < 3; ++x) {
            float a = coord[(size_t)row * 12 + c * 3 + x] - coord[(size_t)col * 12 + c * 3 + x];
            float b = coord[(size_t)row * 12 + f * 3 + x] - coord[(size_t)col * 12 + f * 3 + x];
            rj += a * b;
        }
        p += hqWkr[(size_t)row * 16 + lane] * rj;
    } else if (lane < 32) {
        int j = lane - 16;
        p += hqWkea[(size_t)row * 16 + j] * edge_attr[(size_t)e * 16 + j];
    }
#pragma unroll
    for (int mm = 32; mm; mm >>= 1) p += __shfl_xor(p, mm);
    if (lane == 0) {
        alpha[e] = p;
        atomicAdd(&counts[row], 1);
    }
}

// ---------------------------------------------------------------- exclusive scan (single block, wave scans)
__global__ __launch_bounds__(1024) void k_scan(const int* __restrict__ counts,
                                               int* __restrict__ offsets, int* __restrict__ cursor) {
    __shared__ int wtot[16];
    int t = threadIdx.x;
    int lane = t & 63, wv = t >> 6;
    int base = 0;
    for (int start = 0; start < N_; start += 1024) {
        int i = start + t;
        int orig = (i < N_) ? counts[i] : 0;
        int v = orig;
#pragma unroll
        for (int off = 1; off < 64; off <<= 1) {
            int x = __shfl_up(v, off);
            if (lane >= off) v += x;
        }
        if (lane == 63) wtot[wv] = v;
        __syncthreads();
        int wbase = 0, chunktot = 0;
#pragma unroll
        for (int k = 0; k < 16; ++k) {
            int wt = wtot[k];
            if (k < wv) wbase += wt;
            chunktot += wt;
        }
        if (i < N_) {
            int excl = base + wbase + v - orig;
            offsets[i] = excl;
            cursor[i] = excl;
        }
        base += chunktot;
        __syncthreads();
    }
    if (t == 0) offsets[N_] = base;
}

// ---------------------------------------------------------------- CSR fill
__global__ void k_fill(const int* __restrict__ edge_index, int* __restrict__ cursor,
                       int* __restrict__ edge_ids) {
    int i = blockIdx.x * 256 + threadIdx.x;
    if (i < E_) {
        int r = edge_index[i];
        int pos = atomicAdd(&cursor[r], 1);
        edge_ids[pos] = i;
    }
}

// ---------------------------------------------------------------- per-edge Z[e][4] = silu(u) @ Wc2, MFMA
// 16 edges per wave; u = X(16x32) @ Ccomb(32x512) [MFMA, 32 tiles] + vWc1h[col]
__global__ __launch_bounds__(256, 3) void k_edge_z(
    const int* __restrict__ edge_index, const float* __restrict__ coord,
    const float* __restrict__ edge_attr,
    const float* __restrict__ Cr, const float* __restrict__ Cea, const float* __restrict__ Wc2,
    const u16* __restrict__ vWc1h, float* __restrict__ Z) {
    // B-fragment table: Bf[tile t][lane][j] = bf16(Ccomb[k=(lane>>4)*8+j][jc=t*16+(lane&15)])
    __shared__ __align__(16) u16 Bf[32 * 64 * 8];   // 32 KB
    __shared__ __align__(16) float W2[512 * 4];     // 8 KB, [jc][c] (same layout as Wc2)
    __shared__ __align__(16) u16 Xs[64][16];        // 2 KB radial staging (16 edges per wave)
    int t = threadIdx.x;
    for (int i = t; i < 2048; i += 256) {           // 32 tiles * 64 lanes
        int tile = i >> 6, ln = i & 63;
        int jc = tile * 16 + (ln & 15);
        int k0 = (ln >> 4) * 8;
#pragma unroll
        for (int j = 0; j < 8; ++j) {
            int k = k0 + j;
            float v = (k < 16) ? Cr[(size_t)k * 512 + jc] : Cea[(size_t)(k - 16) * 512 + jc];
            Bf[i * 8 + j] = f2bf(v);
        }
    }
    for (int i = t; i < 2048; i += 256) W2[i] = Wc2[i];
    __syncthreads();
    int wv = t >> 6, lane = t & 63;
    int m = lane & 15, q = lane >> 4;               // A-row (edge) / quad
    int wid = blockIdx.x * 4 + wv;
    int nw = gridDim.x * 4;
    for (int ti = wid; ti < E_ / 16; ti += nw) {
        int e0 = ti * 16;
        // ---- stage radial: 4 edges at a time (16-lane group per edge, q = edge sub-index)
#pragma unroll
        for (int i4 = 0; i4 < 4; ++i4) {
            int e = e0 + i4 * 4 + q;
            int row = edge_index[e], col = edge_index[E_ + e];
            float d = 0.f;
            if (m < 12) d = coord[(size_t)row * 12 + m] - coord[(size_t)col * 12 + m];
            int base = lane & 48;
            int c3 = (m >> 2) * 3, f3 = (m & 3) * 3;
            float r = 0.f;
#pragma unroll
            for (int x = 0; x < 3; ++x) r += __shfl(d, base + c3 + x) * __shfl(d, base + f3 + x);
            Xs[wv * 16 + i4 * 4 + q][m] = f2bf(r);
        }
        // ---- A fragment: k = q*8+j; q<2 -> radial (LDS), q>=2 -> edge_attr (global f32)
        short8 afrag;
        if (q < 2) {
            afrag = *(const short8*)(&Xs[wv * 16 + m][q * 8]);
        } else {
            const float* ea = edge_attr + (size_t)(e0 + m) * 16 + (q - 2) * 8;
#pragma unroll
            for (int j = 0; j < 8; ++j) afrag[j] = (short)f2bf(ea[j]);
        }
        // ---- per-lane C-rows: edges e0 + q*4 + reg
        int cr[4];
#pragma unroll
        for (int reg = 0; reg < 4; ++reg) cr[reg] = edge_index[E_ + e0 + q * 4 + reg];
        float cvp[4][4];
#pragma unroll
        for (int reg = 0; reg < 4; ++reg)
#pragma unroll
            for (int c = 0; c < 4; ++c) cvp[reg][c] = 0.f;
        // ---- 32 MFMA tiles over jc
        for (int tt = 0; tt < 32; ++tt) {
            short8 bfrag = *(const short8*)(Bf + (size_t)(tt * 64 + lane) * 8);
            floatx4 acc = {0.f, 0.f, 0.f, 0.f};
            acc = __builtin_amdgcn_mfma_f32_16x16x32_bf16(afrag, bfrag, acc, 0, 0, 0);
            int jc = tt * 16 + m;
            float4 w2 = *(const float4*)(W2 + jc * 4);
#pragma unroll
            for (int reg = 0; reg < 4; ++reg) {
                float u = acc[reg] + bf2f(vWc1h[(size_t)cr[reg] * 512 + jc]);
                float su = u / (1.f + __expf(-u));
                cvp[reg][0] += su * w2.x;
                cvp[reg][1] += su * w2.y;
                cvp[reg][2] += su * w2.z;
                cvp[reg][3] += su * w2.w;
            }
        }
        // ---- reduce over the 16 jc-lanes of each quad
#pragma unroll
        for (int mm = 1; mm < 16; mm <<= 1)
#pragma unroll
            for (int reg = 0; reg < 4; ++reg)
#pragma unroll
                for (int c = 0; c < 4; ++c) cvp[reg][c] += __shfl_xor(cvp[reg][c], mm);
        if (m < 4) {
#pragma unroll
            for (int reg = 0; reg < 4; ++reg)
                Z[(size_t)(e0 + q * 4 + reg) * 4 + m] = cvp[reg][m];
        }
    }
}

// ---------------------------------------------------------------- per-node softmax + all aggregations (no atomics)
__global__ __launch_bounds__(256) void k_node_main(
    const int* __restrict__ edge_index, const int* __restrict__ offsets, const int* __restrict__ edge_ids,
    const float* __restrict__ alpha, const float* __restrict__ v_h, const float* __restrict__ Z,
    const float* __restrict__ coord, const float* __restrict__ edge_attr, const float* __restrict__ h,
    const float* __restrict__ Wkv, float* __restrict__ h_out, float* __restrict__ coord_out,
    float* __restrict__ att_out) {
    int wv = threadIdx.x >> 6, lane = threadIdx.x & 63;
    int n = blockIdx.x * 4 + wv;
    int beg = offsets[n], end = offsets[n + 1];
    float cn[12];
#pragma unroll
    for (int i = 0; i < 12; ++i) cn[i] = coord[(size_t)n * 12 + i];
    // softmax max
    float mloc = -3.402823466e38f;
    for (int i = beg + lane; i < end; i += 64) mloc = fmaxf(mloc, alpha[edge_ids[i]]);
#pragma unroll
    for (int mm = 32; mm; mm >>= 1) mloc = fmaxf(mloc, __shfl_xor(mloc, mm));
    // softmax sum
    float sloc = 0.f;
    for (int i = beg + lane; i < end; i += 64) sloc += __expf(alpha[edge_ids[i]] - mloc);
#pragma unroll
    for (int mm = 32; mm; mm >>= 1) sloc += __shfl_xor(sloc, mm);
    float inv_s = (end > beg) ? 1.f / sloc : 0.f;
    // lane-parallel pass
    float raggr[16], eaggr[16], cagg[12];
#pragma unroll
    for (int j = 0; j < 16; ++j) { raggr[j] = 0.f; eaggr[j] = 0.f; }
#pragma unroll
    for (int j = 0; j < 12; ++j) cagg[j] = 0.f;
    for (int i = beg + lane; i < end; i += 64) {
        int e = edge_ids[i];
        int col = edge_index[E_ + e];
        float att = __expf(alpha[e] - mloc) * inv_s;
        att_out[e] = att;
        float cd[12];
#pragma unroll
        for (int x = 0; x < 12; ++x) cd[x] = cn[x] - coord[(size_t)col * 12 + x];
#pragma unroll
        for (int c = 0; c < 4; ++c)
#pragma unroll
            for (int f = 0; f < 4; ++f) {
                float r = cd[c * 3] * cd[f * 3] + cd[c * 3 + 1] * cd[f * 3 + 1] + cd[c * 3 + 2] * cd[f * 3 + 2];
                raggr[c * 4 + f] += att * r;
            }
#pragma unroll
        for (int j = 0; j < 16; ++j) eaggr[j] += att * edge_attr[(size_t)e * 16 + j];
        float cv0 = att * Z[(size_t)e * 4 + 0];
        float cv1 = att * Z[(size_t)e * 4 + 1];
        float cv2 = att * Z[(size_t)e * 4 + 2];
        float cv3 = att * Z[(size_t)e * 4 + 3];
#pragma unroll
        for (int x = 0; x < 3; ++x) {
            cagg[0 + x] += cv0 * cd[0 + x];
            cagg[3 + x] += cv1 * cd[3 + x];
            cagg[6 + x] += cv2 * cd[6 + x];
            cagg[9 + x] += cv3 * cd[9 + x];
        }
    }
#pragma unroll
    for (int mm = 32; mm; mm >>= 1) {
#pragma unroll
        for (int j = 0; j < 16; ++j) {
            raggr[j] += __shfl_xor(raggr[j], mm);
            eaggr[j] += __shfl_xor(eaggr[j], mm);
        }
#pragma unroll
        for (int j = 0; j < 12; ++j) cagg[j] += __shfl_xor(cagg[j], mm);
    }
    // wave-cooperative agg (128-dim)
    float agg0 = 0.f, agg1 = 0.f;
    for (int i = beg; i < end; ++i) {
        int e = edge_ids[i];
        int col = edge_index[E_ + e];
        float att = __expf(alpha[e] - mloc) * inv_s;
        agg0 += att * v_h[(size_t)col * 128 + lane];
        agg1 += att * v_h[(size_t)col * 128 + 64 + lane];
    }
#pragma unroll
    for (int g = 0; g < 2; ++g) {
        int dd = g * 64 + lane;
        float acc = g ? agg1 : agg0;
#pragma unroll
        for (int j = 0; j < 16; ++j) {
            acc += raggr[j] * Wkv[(size_t)j * 256 + 2 * dd + 1];
            acc += eaggr[j] * Wkv[(size_t)(144 + j) * 256 + 2 * dd + 1];
        }
        h_out[(size_t)n * 128 + dd] = h[(size_t)n * 128 + dd] + acc;
    }
    if (lane == 0) {
#pragma unroll
        for (int i = 0; i < 12; ++i) {
            float v = fminf(fmaxf(cagg[i], -10.f), 10.f);
            coord_out[(size_t)n * 12 + i] = cn[i] + v;
        }
    }
}

// ================================================================ SLOW (validated) FALLBACK PATH
__global__ __launch_bounds__(256) void k_hq_slow(
    const float* __restrict__ h, const float* __restrict__ Wq, const float* __restrict__ bq,
    float* __restrict__ hq) {
    int idx = blockIdx.x * 256 + threadIdx.x;
    int n = idx >> 7, d = idx & 127;
    float acc = 0.f;
    for (int k = 0; k < 128; ++k) acc += h[(size_t)n * 128 + k] * Wq[k * 128 + d];
    hq[idx] = acc + bq[d];
}

__global__ __launch_bounds__(256) void k_alpha_slow(
    const int* __restrict__ edge_index, const float* __restrict__ coord,
    const float* __restrict__ edge_attr, const float* __restrict__ h,
    const float* __restrict__ Wkv, const float* __restrict__ bkv,
    const float* __restrict__ hq, float* __restrict__ alpha, unsigned int* __restrict__ m) {
    __shared__ float tf[4][160];
    int wv = threadIdx.x >> 6, lane = threadIdx.x & 63;
    int e = blockIdx.x * 4 + wv;
    int row = edge_index[e], col = edge_index[E_ + e];
    if (lane < 16) {
        int c = lane >> 2, f = lane & 3;
        float rj = 0.f;
#pragma unroll
        for (int x = 0; x < 3; ++x) {
            float a = coord[(size_t)row * 12 + c * 3 + x] - coord[(size_t)col * 12 + c * 3 + x];
            float b = coord[(size_t)row * 12 + f * 3 + x] - coord[(size_t)col * 12 + f * 3 + x];
            rj += a * b;
        }
        tf[wv][lane] = rj;
    }
    for (int f = lane; f < 128; f += 64) tf[wv][16 + f] = h[(size_t)col * 128 + f];
    if (lane >= 48) tf[wv][144 + lane - 48] = edge_attr[(size_t)e * 16 + lane - 48];
    __syncthreads();
    float k0 = bkv[2 * lane], k1 = bkv[2 * (64 + lane)];
    for (int f = 0; f < 160; ++f) {
        float tfv = tf[wv][f];
        k0 += tfv * Wkv[f * 256 + 2 * lane];
        k1 += tfv * Wkv[f * 256 + 128 + 2 * lane];
    }
    float p = hq[(size_t)row * 128 + lane] * k0 + hq[(size_t)row * 128 + 64 + lane] * k1;
#pragma unroll
    for (int mm = 32; mm; mm >>= 1) p += __shfl_xor(p, mm);
    if (lane == 0) {
        alpha[e] = p;
        atomicMax(&m[row], fenc(p));
    }
}

__global__ __launch_bounds__(256) void k_expsum_slow(
    const int* __restrict__ edge_index, const float* __restrict__ alpha,
    const unsigned int* __restrict__ m, float* __restrict__ s) {
    int e = blockIdx.x * 256 + threadIdx.x;
    if (e < E_) {
        int row = edge_index[e];
        atomicAdd(&s[row], __expf(alpha[e] - fdec(m[row])));
    }
}

__global__ __launch_bounds__(256) void k_edge2_slow(
    const int* __restrict__ edge_index, const float* __restrict__ coord,
    const float* __restrict__ edge_attr, const float* __restrict__ h,
    const float* __restrict__ Wkv, const float* __restrict__ bkv,
    const float* __restrict__ Wc1, const float* __restrict__ Wc2,
    const float* __restrict__ alpha, const unsigned int* __restrict__ m, const float* __restrict__ s,
    float* __restrict__ agg, float* __restrict__ cagg, float* __restrict__ att_out) {
    __shared__ float tf[4][160];
    __shared__ float vsh[4][128];
    int wv = threadIdx.x >> 6, lane = threadIdx.x & 63;
    int e = blockIdx.x * 4 + wv;
    int row = edge_index[e], col = edge_index[E_ + e];
    if (lane < 16) {
        int c = lane >> 2, f = lane & 3;
        float rj = 0.f;
#pragma unroll
        for (int x = 0; x < 3; ++x) {
            float a = coord[(size_t)row * 12 + c * 3 + x] - coord[(size_t)col * 12 + c * 3 + x];
            float b = coord[(size_t)row * 12 + f * 3 + x] - coord[(size_t)col * 12 + f * 3 + x];
            rj += a * b;
        }
        tf[wv][lane] = rj;
    }
    for (int f = lane; f < 128; f += 64) tf[wv][16 + f] = h[(size_t)col * 128 + f];
    if (lane >= 48) tf[wv][144 + lane - 48] = edge_attr[(size_t)e * 16 + lane - 48];
    __syncthreads();
    float v0 = bkv[2 * lane + 1], v1 = bkv[2 * (64 + lane) + 1];
    for (int f = 0; f < 160; ++f) {
        float tfv = tf[wv][f];
        v0 += tfv * Wkv[f * 256 + 2 * lane + 1];
        v1 += tfv * Wkv[f * 256 + 129 + 2 * lane];
    }
    float att = __expf(alpha[e] - fdec(m[row])) / s[row];
    atomicAdd(&agg[(size_t)row * 128 + lane], att * v0);
    atomicAdd(&agg[(size_t)row * 128 + 64 + lane], att * v1);
    vsh[wv][lane] = v0;
    vsh[wv][64 + lane] = v1;
    __syncthreads();
    float cv[4] = {0.f, 0.f, 0.f, 0.f};
    for (int g = 0; g < 8; ++g) {
        int jc = g * 64 + lane;
        float u = 0.f;
        for (int dd = 0; dd < 128; ++dd) u += vsh[wv][dd] * Wc1[dd * 512 + jc];
        float su = u / (1.f + __expf(-u));
#pragma unroll
        for (int c = 0; c < 4; ++c) cv[c] += su * Wc2[jc * 4 + c];
    }
#pragma unroll
    for (int mm = 32; mm; mm >>= 1)
#pragma unroll
        for (int c = 0; c < 4; ++c) cv[c] += __shfl_xor(cv[c], mm);
    if (lane < 12) {
        int c = lane / 3;
        float cd = coord[(size_t)row * 12 + lane] - coord[(size_t)col * 12 + lane];
        atomicAdd(&cagg[(size_t)row * 12 + lane], att * cv[c] * cd);
    }
    if (lane == 0) att_out[e] = att;
}

__global__ __launch_bounds__(256) void k_final_slow(
    const float* __restrict__ h, const float* __restrict__ coord,
    const float* __restrict__ agg, const float* __restrict__ cagg,
    float* __restrict__ h_out, float* __restrict__ coord_out) {
    int idx = blockIdx.x * 256 + threadIdx.x;
    h_out[idx] = h[idx] + agg[idx];
    if (idx < N_ * 12) {
        float v = fminf(fmaxf(cagg[idx], -10.f), 10.f);
        coord_out[idx] = coord[idx] + v;
    }
}

// ---------------------------------------------------------------- launch
extern "C" void kernel_launch(void* const* d_in, const int* in_sizes, int n_in,
                              void* d_out, int out_size, void* d_ws, size_t ws_size,
                              hipStream_t stream) {
    (void)in_sizes; (void)n_in; (void)out_size;
    const float* h          = (const float*)d_in[0];
    const float* coord      = (const float*)d_in[1];
    const int*   edge_index = (const int*)d_in[2];
    const float* edge_attr  = (const float*)d_in[3];
    const float* Wq         = (const float*)d_in[4];
    const float* bq         = (const float*)d_in[5];
    const float* Wkv        = (const float*)d_in[6];
    const float* bkv        = (const float*)d_in[7];
    const float* Wc1        = (const float*)d_in[8];
    const float* Wc2        = (const float*)d_in[9];

    float* out = (float*)d_out;
    float* h_out = out;
    float* coord_out = out + (size_t)N_ * 128;
    float* att_out = coord_out + (size_t)N_ * 12;

    char* w = (char*)d_ws;
    size_t off = 0;
    auto alloc = [&](size_t bytes) -> void* {
        void* p = w + off;
        off += (bytes + 255) & ~(size_t)255;
        return p;
    };
    // ---- fast-path layout
    int* counts   = (int*)alloc((size_t)N_ * 4);          // zeroed
    float* hq     = (float*)alloc((size_t)N_ * 128 * 4);
    float* k_h    = (float*)alloc((size_t)N_ * 128 * 4);
    float* v_h    = (float*)alloc((size_t)N_ * 128 * 4);
    u16*   vWc1h  = (u16*)alloc((size_t)N_ * 512 * 2);
    float* hqWkr  = (float*)alloc((size_t)N_ * 16 * 4);
    float* hqWkea = (float*)alloc((size_t)N_ * 16 * 4);
    float* alpha  = (float*)alloc((size_t)E_ * 4);
    float* Z      = (float*)alloc((size_t)E_ * 4 * 4);
    float* Cr     = (float*)alloc(16 * 512 * 4);
    float* Cea    = (float*)alloc(16 * 512 * 4);
    int* offsets  = (int*)alloc((size_t)(N_ + 1) * 4);
    int* cursor   = (int*)alloc((size_t)N_ * 4);
    int* edge_ids = (int*)alloc((size_t)E_ * 4);
    size_t fast_req = off;

    if (ws_size >= fast_req) {
        hipLaunchKernelGGL(k_zero, dim3((N_ + 255) / 256), dim3(256), 0, stream,
                           (unsigned int*)counts, N_);
        hipLaunchKernelGGL(k_node1, dim3(N_ / 8), dim3(256), 0, stream,
                           h, Wq, bq, Wkv, bkv, hq, k_h, v_h);
        hipLaunchKernelGGL(k_composites, dim3(64), dim3(256), 0, stream, Wkv, Wc1, Cr, Cea);
        hipLaunchKernelGGL(k_hqw, dim3(N_ * 32 / 256), dim3(256), 0, stream, hq, Wkv, hqWkr, hqWkea);
        hipLaunchKernelGGL(k_vwc1, dim3(N_ / 8), dim3(256), 0, stream, v_h, Wc1, vWc1h);
        hipLaunchKernelGGL(k_alpha_fast, dim3(E_ / 4), dim3(256), 0, stream,
                           edge_index, coord, edge_attr, hq, k_h, hqWkr, hqWkea, alpha, counts);
        hipLaunchKernelGGL(k_scan, dim3(1), dim3(1024), 0, stream, counts, offsets, cursor);
        hipLaunchKernelGGL(k_fill, dim3((E_ + 255) / 256), dim3(256), 0, stream,
                           edge_index, cursor, edge_ids);
        hipLaunchKernelGGL(k_edge_z, dim3(768), dim3(256), 0, stream,
                           edge_index, coord, edge_attr, Cr, Cea, Wc2, vWc1h, Z);
        hipLaunchKernelGGL(k_node_main, dim3(N_ / 4), dim3(256), 0, stream,
                           edge_index, offsets, edge_ids, alpha, v_h, Z, coord, edge_attr, h,
                           Wkv, h_out, coord_out, att_out);
    } else {
        // ---- slow validated path (separate layout from offset 0)
        off = 0;
        float* s        = (float*)alloc((size_t)N_ * 4);
        unsigned int* m = (unsigned int*)alloc((size_t)N_ * 4);
        float* agg      = (float*)alloc((size_t)N_ * 128 * 4);
        float* cagg     = (float*)alloc((size_t)N_ * 12 * 4);
        size_t zb       = off;
        float* hq2      = (float*)alloc((size_t)N_ * 128 * 4);
        float* alpha2   = (float*)alloc((size_t)E_ * 4);
        int zero_n = (int)(zb / 4);
        hipLaunchKernelGGL(k_zero, dim3((zero_n + 255) / 256), dim3(256), 0, stream,
                           (unsigned int*)s, zero_n);
        hipLaunchKernelGGL(k_hq_slow, dim3(N_ * 128 / 256), dim3(256), 0, stream, h, Wq, bq, hq2);
        hipLaunchKernelGGL(k_alpha_slow, dim3(E_ / 4), dim3(256), 0, stream,
                           edge_index, coord, edge_attr, h, Wkv, bkv, hq2, alpha2, m);
        hipLaunchKernelGGL(k_expsum_slow, dim3((E_ + 255) / 256), dim3(256), 0, stream,
                           edge_index, alpha2, m, s);
        hipLaunchKernelGGL(k_edge2_slow, dim3(E_ / 4), dim3(256), 0, stream,
                           edge_index, coord, edge_attr, h, Wkv, bkv, Wc1, Wc2,
                           alpha2, m, s, agg, cagg, att_out);
        hipLaunchKernelGGL(k_final_slow, dim3(N_ * 128 / 256), dim3(256), 0, stream,
                           h, coord, agg, cagg, h_out, coord_out);
    }
}